// Round 7
// baseline (403.240 us; speedup 1.0000x reference)
//
#include <hip/hip_runtime.h>
#include <stdint.h>

#define BTOK 16384
#define DM   512
#define DFF  2048
#define NE   8
#define NPAIR (BTOK*2)
#define MAXT 288          // max 128-row tiles total (balanced: ~264)
#define TPXMAX 36         // ceil(MAXT/8): per-XCD tile chunk upper bound

typedef short s16x8 __attribute__((ext_vector_type(8)));   // 8 bf16 in 4 VGPRs
typedef float f32x4 __attribute__((ext_vector_type(4)));

// fp32 -> bf16 RNE (inputs finite)
__device__ __forceinline__ uint16_t f2b(float f) {
  uint32_t u = __float_as_uint(f);
  u += 0x7fff + ((u >> 16) & 1);
  return (uint16_t)(u >> 16);
}

// async global->LDS, 16B per lane; lds ptr must be wave-uniform base (HW adds lane*16)
__device__ __forceinline__ void g2l16(const void* gp, void* lp) {
  __builtin_amdgcn_global_load_lds(
      (__attribute__((address_space(1))) void*)(void*)gp,
      (__attribute__((address_space(3))) void*)lp, 16, 0, 0);
}

// ---------- transpose+convert, VECTORIZED 16B stores (was 2B scalar: 32x under-vectorized) ----------
// z<8 -> W1 [D][DFF]->[DFF][D], z>=8 -> W2 [DFF][D]->[D][DFF]
__global__ void k_tr(const float* __restrict__ w1, const float* __restrict__ w2,
                     uint16_t* __restrict__ w1t, uint16_t* __restrict__ w2t) {
  __shared__ float t[32][33];
  int z = blockIdx.z, bx = blockIdx.x;
  int R, C, c0, r0;
  const float* src;
  uint16_t* dst;
  if (z < 8) { R = DM; C = DFF; c0 = (bx & 63) * 32; r0 = (bx >> 6) * 32;
               src = w1 + (size_t)z * R * C; dst = w1t + (size_t)z * R * C; }
  else       { R = DFF; C = DM; c0 = (bx & 15) * 32; r0 = (bx >> 4) * 32;
               src = w2 + (size_t)(z - 8) * R * C; dst = w2t + (size_t)(z - 8) * R * C; }
  int tx = threadIdx.x, ty = threadIdx.y;       // 32 x 8
#pragma unroll
  for (int j = 0; j < 4; j++)
    t[ty + j * 8][tx] = src[(size_t)(r0 + ty + j * 8) * C + c0 + tx];
  __syncthreads();
  int tid = ty * 32 + tx;
  int oc = tid >> 3, ch = tid & 7;              // output row oc (= src col), 16B chunk ch
  if (ch < 4) {
    uint16_t v[8];
#pragma unroll
    for (int k = 0; k < 8; k++) v[k] = f2b(t[ch * 8 + k][oc]);
    *(s16x8*)(dst + (size_t)(c0 + oc) * R + r0 + ch * 8) = *(s16x8*)v;
  }
}

// ---- gate + x->bf16: wave-per-token x16, wg in registers, LDS histogram; then convert block's x slab ----
__global__ __launch_bounds__(256) void k_route(const float* __restrict__ x,
                                               const float* __restrict__ wg,
                                               int* __restrict__ counts,
                                               int* __restrict__ tk_e, float* __restrict__ tk_w,
                                               uint16_t* __restrict__ xb) {
  __shared__ int hist[NE];
  int tid = threadIdx.x, lane = tid & 63, wave = tid >> 6;
  if (tid < NE) hist[tid] = 0;
  __syncthreads();

  float wv[8][8];
#pragma unroll
  for (int j = 0; j < 8; j++) {
    const float4* wr = (const float4*)(wg + (size_t)(j * 64 + lane) * NE);
    float4 a = wr[0], b = wr[1];
    wv[j][0] = a.x; wv[j][1] = a.y; wv[j][2] = a.z; wv[j][3] = a.w;
    wv[j][4] = b.x; wv[j][5] = b.y; wv[j][6] = b.z; wv[j][7] = b.w;
  }

  int tok0 = blockIdx.x * 64 + wave * 16;
  for (int tt = 0; tt < 16; tt++) {
    int tok = tok0 + tt;
    const float* xr = x + (size_t)tok * DM;
    float xv[8];
#pragma unroll
    for (int j = 0; j < 8; j++) xv[j] = xr[j * 64 + lane];
    float acc[NE];
#pragma unroll
    for (int e = 0; e < NE; e++) acc[e] = 0.f;
#pragma unroll
    for (int j = 0; j < 8; j++)
#pragma unroll
      for (int e = 0; e < NE; e++) acc[e] += xv[j] * wv[j][e];
#pragma unroll
    for (int e = 0; e < NE; e++) {
#pragma unroll
      for (int off = 32; off > 0; off >>= 1) acc[e] += __shfl_xor(acc[e], off, 64);
    }
    if (lane == 0) {
      float mx = acc[0];
      for (int e = 1; e < NE; e++) mx = fmaxf(mx, acc[e]);
      float p[NE], s = 0.f;
      for (int e = 0; e < NE; e++) { p[e] = __expf(acc[e] - mx); s += p[e]; }
      float inv = 1.f / s;
      int e0 = 0; float v0 = p[0];
      for (int e = 1; e < NE; e++) if (p[e] > v0) { v0 = p[e]; e0 = e; }  // strict > = top_k tiebreak
      int e1 = -1; float v1 = -1.f;
      for (int e = 0; e < NE; e++) if (e != e0 && p[e] > v1) { v1 = p[e]; e1 = e; }
      tk_e[tok * 2]     = e0; tk_w[tok * 2]     = v0 * inv;
      tk_e[tok * 2 + 1] = e1; tk_w[tok * 2 + 1] = v1 * inv;
      atomicAdd(&hist[e0], 1);
      atomicAdd(&hist[e1], 1);
    }
  }
  // convert this block's 64-token slab (L2-hot) to bf16
  const float* xs = x + (size_t)blockIdx.x * 32768;
  uint16_t* xd = xb + (size_t)blockIdx.x * 32768;
#pragma unroll
  for (int i = 0; i < 16; i++) {
    int o = i * 2048 + tid * 8;
    float4 a = *(const float4*)(xs + o);
    float4 b = *(const float4*)(xs + o + 4);
    uint16_t v[8] = {f2b(a.x), f2b(a.y), f2b(a.z), f2b(a.w),
                     f2b(b.x), f2b(b.y), f2b(b.z), f2b(b.w)};
    *(s16x8*)(xd + o) = *(s16x8*)v;
  }
  __syncthreads();
  if (tid < NE) atomicAdd(&counts[tid], hist[tid]);
}

// ---------------- prefix sums + 128-row tile map — PARALLELIZED (was 1-thread serial ~270 iters) ----------------
__global__ void k_setup(const int* __restrict__ counts, int* __restrict__ offsets,
                        int* __restrict__ trB, int* __restrict__ texp, int* __restrict__ ntB) {
  __shared__ int soff[NE + 1], ts[NE + 1];
  int tid = threadIdx.x;
  if (tid == 0) {
    int off = 0;
    for (int e = 0; e < NE; e++) { soff[e] = off; offsets[e] = off; off += counts[e]; }
    soff[NE] = off; offsets[NE] = off;
    int nt = 0;
    for (int e = 0; e < NE; e++) { ts[e] = nt; nt += (counts[e] + 127) >> 7; }
    ts[NE] = nt; *ntB = nt;
  }
  __syncthreads();
  if (tid < NE) {
    int e = tid, base = ts[e], o = soff[e];
    int n = ts[e + 1] - ts[e];
    for (int i = 0; i < n; i++) { trB[base + i] = o + i * 128; texp[base + i] = e; }
  }
}

// ------- build compact slot lists (inv map dropped: combine is fused into gemm2) -------
__global__ __launch_bounds__(256) void k_build(const int* __restrict__ tk_e, const float* __restrict__ tk_w,
                                               const int* __restrict__ offsets, int* __restrict__ cursors,
                                               int* __restrict__ tok_of, float* __restrict__ w_of) {
  __shared__ int lcnt[NE], lbase[NE];
  int tid = threadIdx.x;
  int i = blockIdx.x * 256 + tid;
  if (tid < NE) lcnt[tid] = 0;
  __syncthreads();
  int e = tk_e[i];
  int local = atomicAdd(&lcnt[e], 1);
  __syncthreads();
  if (tid < NE) lbase[tid] = atomicAdd(&cursors[tid], lcnt[tid]);
  __syncthreads();
  int slot = offsets[e] + lbase[e] + local;
  tok_of[slot] = i >> 1;
  w_of[slot] = tk_w[i];
}

// =====================================================================================
// Pipelined GEMM core (round-6, passing, unchanged): 128x256 tile, 4 waves (2x2),
// wave tile 64x128, acc[4][8], BK=32, 3-deep LDS ring (72KB) -> 2 blocks/CU, counted
// vmcnt (VM6 steady), conflict-free granule swizzle (PMC=0).
// NEW: XCD-chunked block map (T1): id&7 = XCD (HW round-robin); each XCD owns a
// contiguous tile chunk and iterates all n0 of a tile consecutively -> A-slab and
// per-expert W panels stay in that XCD's L2 (round-6 map spread them across 8 XCDs;
// FETCH_SIZE 139MB for a 54MB working set).
// =====================================================================================

#define LDS16(off) (*(const s16x8*)((const char*)smem + (off)))
#define VM6 asm volatile("s_waitcnt vmcnt(6)" ::: "memory")
#define VM0 asm volatile("s_waitcnt vmcnt(0)" ::: "memory")
#define NOVM do{}while(0)
#define NOSTG do{}while(0)
#define MFMA16 __builtin_amdgcn_mfma_f32_16x16x32_bf16
#define BSTR 24576

#define DS0_P(bb) do{ \
  bf0 = LDS16(offB0 + (bb)*BSTR); bf1 = LDS16(offB1 + (bb)*BSTR); \
  bf2 = LDS16(offB2 + (bb)*BSTR); bf3 = LDS16(offB3 + (bb)*BSTR); \
  bf4 = LDS16(offB4 + (bb)*BSTR); bf5 = LDS16(offB5 + (bb)*BSTR); \
  bf6 = LDS16(offB6 + (bb)*BSTR); bf7 = LDS16(offB7 + (bb)*BSTR); \
  af0 = LDS16(offA0 + (bb)*BSTR); af1 = LDS16(offA1 + (bb)*BSTR); }while(0)
#define DS1_P(bb) do{ \
  af2 = LDS16(offA2 + (bb)*BSTR); af3 = LDS16(offA3 + (bb)*BSTR); }while(0)
#define SA_P(bb) do{ \
  g2l16(gA0, (char*)smem + (bb)*BSTR + wave*1024); \
  g2l16(gA1, (char*)smem + (bb)*BSTR + 4096 + wave*1024); \
  gA0 += 32; gA1 += 32; }while(0)
#define SB_P(bb) do{ \
  g2l16(gB0, (char*)smem + (bb)*BSTR + 8192 + wave*1024); \
  g2l16(gB1, (char*)smem + (bb)*BSTR + 12288 + wave*1024); \
  g2l16(gB2, (char*)smem + (bb)*BSTR + 16384 + wave*1024); \
  g2l16(gB3, (char*)smem + (bb)*BSTR + 20480 + wave*1024); \
  gB0 += 32; gB1 += 32; gB2 += 32; gB3 += 32; }while(0)
#define MM16A do{ \
  __builtin_amdgcn_s_setprio(1); \
  acc[0][0] = MFMA16(af0, bf0, acc[0][0], 0, 0, 0); \
  acc[1][0] = MFMA16(af1, bf0, acc[1][0], 0, 0, 0); \
  acc[0][1] = MFMA16(af0, bf1, acc[0][1], 0, 0, 0); \
  acc[1][1] = MFMA16(af1, bf1, acc[1][1], 0, 0, 0); \
  acc[0][2] = MFMA16(af0, bf2, acc[0][2], 0, 0, 0); \
  acc[1][2] = MFMA16(af1, bf2, acc[1][2], 0, 0, 0); \
  acc[0][3] = MFMA16(af0, bf3, acc[0][3], 0, 0, 0); \
  acc[1][3] = MFMA16(af1, bf3, acc[1][3], 0, 0, 0); \
  acc[0][4] = MFMA16(af0, bf4, acc[0][4], 0, 0, 0); \
  acc[1][4] = MFMA16(af1, bf4, acc[1][4], 0, 0, 0); \
  acc[0][5] = MFMA16(af0, bf5, acc[0][5], 0, 0, 0); \
  acc[1][5] = MFMA16(af1, bf5, acc[1][5], 0, 0, 0); \
  acc[0][6] = MFMA16(af0, bf6, acc[0][6], 0, 0, 0); \
  acc[1][6] = MFMA16(af1, bf6, acc[1][6], 0, 0, 0); \
  acc[0][7] = MFMA16(af0, bf7, acc[0][7], 0, 0, 0); \
  acc[1][7] = MFMA16(af1, bf7, acc[1][7], 0, 0, 0); \
  __builtin_amdgcn_s_setprio(0); }while(0)
#define MM16B do{ \
  __builtin_amdgcn_s_setprio(1); \
  acc[2][0] = MFMA16(af2, bf0, acc[2][0], 0, 0, 0); \
  acc[3][0] = MFMA16(af3, bf0, acc[3][0], 0, 0, 0); \
  acc[2][1] = MFMA16(af2, bf1, acc[2][1], 0, 0, 0); \
  acc[3][1] = MFMA16(af3, bf1, acc[3][1], 0, 0, 0); \
  acc[2][2] = MFMA16(af2, bf2, acc[2][2], 0, 0, 0); \
  acc[3][2] = MFMA16(af3, bf2, acc[3][2], 0, 0, 0); \
  acc[2][3] = MFMA16(af2, bf3, acc[2][3], 0, 0, 0); \
  acc[3][3] = MFMA16(af3, bf3, acc[3][3], 0, 0, 0); \
  acc[2][4] = MFMA16(af2, bf4, acc[2][4], 0, 0, 0); \
  acc[3][4] = MFMA16(af3, bf4, acc[3][4], 0, 0, 0); \
  acc[2][5] = MFMA16(af2, bf5, acc[2][5], 0, 0, 0); \
  acc[3][5] = MFMA16(af3, bf5, acc[3][5], 0, 0, 0); \
  acc[2][6] = MFMA16(af2, bf6, acc[2][6], 0, 0, 0); \
  acc[3][6] = MFMA16(af3, bf6, acc[3][6], 0, 0, 0); \
  acc[2][7] = MFMA16(af2, bf7, acc[2][7], 0, 0, 0); \
  acc[3][7] = MFMA16(af3, bf7, acc[3][7], 0, 0, 0); \
  __builtin_amdgcn_s_setprio(0); }while(0)
#define TILEP(bb, SA, SB, VMX) do{ \
  DS0_P(bb); SA; \
  __builtin_amdgcn_s_barrier(); \
  asm volatile("s_waitcnt lgkmcnt(0)" ::: "memory"); \
  MM16A; \
  __builtin_amdgcn_s_barrier(); \
  DS1_P(bb); SB; \
  __builtin_amdgcn_s_barrier(); \
  asm volatile("s_waitcnt lgkmcnt(0)" ::: "memory"); \
  MM16B; \
  VMX; \
  __builtin_amdgcn_s_barrier(); }while(0)

// common per-thread geometry (4 waves, 256 threads)
#define GEOM_SETUP \
  int tid = threadIdx.x, lane = tid & 63, wave = tid >> 6; \
  int wm = wave >> 1, wn = wave & 1; \
  int l15 = lane & 15, l4 = lane >> 4; \
  int offA0, offA1, offA2, offA3; \
  int offB0, offB1, offB2, offB3, offB4, offB5, offB6, offB7; \
  { int r; \
    r = wm*64 + 0*16 + l15; offA0 = r*64 + ((l4 ^ ((r>>1)&3)) << 4); \
    r = wm*64 + 1*16 + l15; offA1 = r*64 + ((l4 ^ ((r>>1)&3)) << 4); \
    r = wm*64 + 2*16 + l15; offA2 = r*64 + ((l4 ^ ((r>>1)&3)) << 4); \
    r = wm*64 + 3*16 + l15; offA3 = r*64 + ((l4 ^ ((r>>1)&3)) << 4); \
    r = wn*128 + 0*16 + l15; offB0 = 8192 + r*64 + ((l4 ^ ((r>>1)&3)) << 4); \
    r = wn*128 + 1*16 + l15; offB1 = 8192 + r*64 + ((l4 ^ ((r>>1)&3)) << 4); \
    r = wn*128 + 2*16 + l15; offB2 = 8192 + r*64 + ((l4 ^ ((r>>1)&3)) << 4); \
    r = wn*128 + 3*16 + l15; offB3 = 8192 + r*64 + ((l4 ^ ((r>>1)&3)) << 4); \
    r = wn*128 + 4*16 + l15; offB4 = 8192 + r*64 + ((l4 ^ ((r>>1)&3)) << 4); \
    r = wn*128 + 5*16 + l15; offB5 = 8192 + r*64 + ((l4 ^ ((r>>1)&3)) << 4); \
    r = wn*128 + 6*16 + l15; offB6 = 8192 + r*64 + ((l4 ^ ((r>>1)&3)) << 4); \
    r = wn*128 + 7*16 + l15; offB7 = 8192 + r*64 + ((l4 ^ ((r>>1)&3)) << 4); \
  } \
  int rp = tid >> 2, cp = (tid & 3) ^ ((rp >> 1) & 3);  /* stage: row rp(+64k), slot tid&3 */

#define ACC_INIT \
  f32x4 acc[4][8]; \
  _Pragma("unroll") for (int m = 0; m < 4; m++) \
  _Pragma("unroll") for (int n = 0; n < 8; n++) \
  _Pragma("unroll") for (int i = 0; i < 4; i++) acc[m][n][i] = 0.f; \
  s16x8 af0, af1, af2, af3, bf0, bf1, bf2, bf3, bf4, bf5, bf6, bf7;

// ---------- GEMM1: h[slot][DFF] = relu(x[tok] @ W1[e] + b1[e]); K=512, NT=16 ----------
__global__ __launch_bounds__(256, 2) void k_gemm1(
    const uint16_t* __restrict__ xb, const uint16_t* __restrict__ w1t,
    const float* __restrict__ b1,
    const int* __restrict__ tok_of, const int* __restrict__ offsets,
    const int* __restrict__ trB, const int* __restrict__ texp, const int* __restrict__ ntB,
    uint16_t* __restrict__ h) {
  __shared__ __align__(16) uint16_t smem[36864];   // 72KB: 3 bufs x (A 8KB + B 16KB)
  // XCD-chunked map: x = id&7 (HW round-robin XCD), each XCD owns tpx contiguous tiles,
  // iterating the 8 n0 of one tile consecutively (A-slab + W1 panel L2-resident per XCD).
  int id = blockIdx.x;
  int nt = *ntB, tpx = (nt + 7) >> 3;
  int x = id & 7, q = id >> 3, j = q >> 3;
  if (j >= tpx) return;
  int tile = x * tpx + j;
  if (tile >= nt) return;
  int n0 = (q & 7) * 256;
  int e = texp[tile], row0 = trB[tile], end = offsets[e + 1];
  GEOM_SETUP;

  const uint16_t *gA0, *gA1, *gB0, *gB1, *gB2, *gB3;
  { int s0 = row0 + rp;      if (s0 >= end) s0 = end - 1;
    int s1 = row0 + rp + 64; if (s1 >= end) s1 = end - 1;
    gA0 = xb + (size_t)tok_of[s0] * DM + cp * 8;
    gA1 = xb + (size_t)tok_of[s1] * DM + cp * 8; }
  { const uint16_t* wb = w1t + (size_t)e * DFF * DM;
    gB0 = wb + (size_t)(n0 + rp +   0) * DM + cp * 8;
    gB1 = wb + (size_t)(n0 + rp +  64) * DM + cp * 8;
    gB2 = wb + (size_t)(n0 + rp + 128) * DM + cp * 8;
    gB3 = wb + (size_t)(n0 + rp + 192) * DM + cp * 8; }

  ACC_INIT;

  SA_P(0); SB_P(0); SA_P(1); SB_P(1);
  VM6;
  __builtin_amdgcn_s_barrier();

#pragma unroll 1
  for (int g = 0; g < 4; ++g) {                    // tiles 0..11 (NT=16)
    TILEP(0, SA_P(2), SB_P(2), VM6);
    TILEP(1, SA_P(0), SB_P(0), VM6);
    TILEP(2, SA_P(1), SB_P(1), VM6);
  }
  TILEP(0, SA_P(2), SB_P(2), VM6);                 // tile 12 stages 14
  TILEP(1, SA_P(0), SB_P(0), VM6);                 // tile 13 stages 15
  TILEP(2, NOSTG, NOSTG, VM0);                     // tile 14
  TILEP(0, NOSTG, NOSTG, NOVM);                    // tile 15

  // epilogue: bias+relu -> bf16, per-wave LDS repack (row stride 272B: 16B-aligned, bank-spread)
  {
    float bv[8];
#pragma unroll
    for (int n = 0; n < 8; n++) bv[n] = b1[(size_t)e * DFF + n0 + wn * 128 + n * 16 + l15];
    char* wrg = (char*)smem + wave * 4608;
    int rr = lane >> 2, cb = lane & 3;
#pragma unroll
    for (int m = 0; m < 4; m++) {
#pragma unroll
      for (int n = 0; n < 8; n++)
#pragma unroll
        for (int i = 0; i < 4; i++) {
          float v = fmaxf(acc[m][n][i] + bv[n], 0.f);
          *(uint16_t*)(wrg + (l4 * 4 + i) * 272 + (n * 16 + l15) * 2) = f2b(v);
        }
      int gr = row0 + wm * 64 + m * 16 + rr;
      const char* src = wrg + rr * 272 + cb * 64;
      if (gr < end) {
        uint16_t* dst = h + (size_t)gr * DFF + n0 + wn * 128 + cb * 32;
        *(s16x8*)(dst +  0) = *(const s16x8*)(src +  0);
        *(s16x8*)(dst +  8) = *(const s16x8*)(src + 16);
        *(s16x8*)(dst + 16) = *(const s16x8*)(src + 32);
        *(s16x8*)(dst + 24) = *(const s16x8*)(src + 48);
      }
    }
  }
}

// ---------- GEMM2: out[tok] += w_of[slot]*(h[slot] @ W2[e] + b2[e]); K=2048, NT=64 ----------
// Combine FUSED: TOPK=2 => each out element gets exactly 2 atomic fp32 adds onto 0;
// two-term fp add is commutative bit-exactly, so order nondeterminism is harmless.
__global__ __launch_bounds__(256, 2) void k_gemm2(
    const uint16_t* __restrict__ h, const uint16_t* __restrict__ w2t,
    const float* __restrict__ b2, const float* __restrict__ w_of,
    const int* __restrict__ tok_of, const int* __restrict__ offsets,
    const int* __restrict__ trB, const int* __restrict__ texp, const int* __restrict__ ntB,
    float* __restrict__ out) {
  __shared__ __align__(16) uint16_t smem[36864];   // 72KB: 3 bufs x (A 8KB + B 16KB)
  int id = blockIdx.x;
  int nt = *ntB, tpx = (nt + 7) >> 3;
  int x = id & 7, q = id >> 3, j = q >> 1;
  if (j >= tpx) return;
  int tile = x * tpx + j;
  if (tile >= nt) return;
  int n0 = (q & 1) * 256;
  int e = texp[tile], row0 = trB[tile], end = offsets[e + 1];
  GEOM_SETUP;

  const uint16_t *gA0, *gA1, *gB0, *gB1, *gB2, *gB3;
  { int s0 = row0 + rp;      if (s0 >= end) s0 = end - 1;
    int s1 = row0 + rp + 64; if (s1 >= end) s1 = end - 1;
    gA0 = h + (size_t)s0 * DFF + cp * 8;
    gA1 = h + (size_t)s1 * DFF + cp * 8; }
  { const uint16_t* wb = w2t + (size_t)e * DM * DFF;
    gB0 = wb + (size_t)(n0 + rp +   0) * DFF + cp * 8;
    gB1 = wb + (size_t)(n0 + rp +  64) * DFF + cp * 8;
    gB2 = wb + (size_t)(n0 + rp + 128) * DFF + cp * 8;
    gB3 = wb + (size_t)(n0 + rp + 192) * DFF + cp * 8; }

  ACC_INIT;

  SA_P(0); SB_P(0); SA_P(1); SB_P(1);
  VM6;
  __builtin_amdgcn_s_barrier();

#pragma unroll 1
  for (int g = 0; g < 20; ++g) {                   // tiles 0..59 (NT=64)
    TILEP(0, SA_P(2), SB_P(2), VM6);
    TILEP(1, SA_P(0), SB_P(0), VM6);
    TILEP(2, SA_P(1), SB_P(1), VM6);
  }
  TILEP(0, SA_P(2), SB_P(2), VM6);                 // tile 60 stages 62
  TILEP(1, SA_P(0), SB_P(0), VM6);                 // tile 61 stages 63
  TILEP(2, NOSTG, NOSTG, VM0);                     // tile 62
  TILEP(0, NOSTG, NOSTG, NOVM);                    // tile 63

  // epilogue: weighted bias add, atomicAdd into out (combine fused)
  {
    float bv[8];
#pragma unroll
    for (int n = 0; n < 8; n++) bv[n] = b2[(size_t)e * DM + n0 + wn * 128 + n * 16 + l15];
#pragma unroll
    for (int m = 0; m < 4; m++)
#pragma unroll
      for (int i = 0; i < 4; i++) {
        int slot = row0 + wm * 64 + m * 16 + l4 * 4 + i;
        if (slot < end) {
          float wgt = w_of[slot];
          int tok = tok_of[slot];
          float* ob = out + (size_t)tok * DM + n0 + wn * 128 + l15;
#pragma unroll
          for (int n = 0; n < 8; n++) atomicAdd(ob + n * 16, wgt * (acc[m][n][i] + bv[n]));
        }
      }
  }
}

extern "C" void kernel_launch(void* const* d_in, const int* in_sizes, int n_in,
                              void* d_out, int out_size, void* d_ws, size_t ws_size,
                              hipStream_t stream) {
  const float* x  = (const float*)d_in[0];
  const float* wg = (const float*)d_in[1];
  const float* w1 = (const float*)d_in[2];
  const float* b1 = (const float*)d_in[3];
  const float* w2 = (const float*)d_in[4];
  const float* b2 = (const float*)d_in[5];
  float* out = (float*)d_out;

  char* ws = (char*)d_ws;
  const size_t MB = 1024 * 1024;
  uint16_t* xb   = (uint16_t*)ws;                  // [0,16) MB
  uint16_t* w1t  = (uint16_t*)(ws + 16 * MB);      // [16,32) MB  [E][DFF][DM]
  uint16_t* w2t  = (uint16_t*)(ws + 32 * MB);      // [32,48) MB  [E][DM][DFF]
  uint16_t* hbuf = (uint16_t*)(ws + 48 * MB);      // [48,176) MB [NPAIR][DFF]
  int* ctrl = (int*)(ws + 176 * MB);               // [176,177) MB
  int*   counts  = ctrl;                 // 0..8
  int*   cursors = ctrl + 8;             // 8..16
  int*   offsets = ctrl + 16;            // 16..25
  int*   ntB     = ctrl + 32;            // 32
  int*   trB     = ctrl + 64;            // 64..384 (320)
  int*   texp    = ctrl + 384;           // 384..704 (320)
  int*   tk_e    = ctrl + 1024;
  float* tk_w    = (float*)(ctrl + 1024 + 32768);
  int*   tok_of  = ctrl + 1024 + 2 * 32768;
  float* w_of    = (float*)(ctrl + 1024 + 3 * 32768);

  hipMemsetAsync(counts, 0, 16 * sizeof(int), stream);
  hipMemsetAsync(d_out, 0, out_size, stream);      // gemm2 accumulates into out

  k_route<<<BTOK / 64, 256, 0, stream>>>(x, wg, counts, tk_e, tk_w, xb);
  k_tr<<<dim3(1024, 1, 16), dim3(32, 8), 0, stream>>>(w1, w2, w1t, w2t);
  k_setup<<<1, 64, 0, stream>>>(counts, offsets, trB, texp, ntB);
  k_build<<<NPAIR / 256, 256, 0, stream>>>(tk_e, tk_w, offsets, cursors, tok_of, w_of);
  k_gemm1<<<8 * TPXMAX * 8, 256, 0, stream>>>(xb, w1t, b1, tok_of, offsets,
                                              trB, texp, ntB, hbuf);
  k_gemm2<<<8 * TPXMAX * 2, 256, 0, stream>>>(hbuf, w2t, b2, w_of, tok_of, offsets,
                                              trB, texp, ntB, out);
}

// Round 8
// 383.138 us; speedup vs baseline: 1.0525x; 1.0525x over previous
//
#include <hip/hip_runtime.h>
#include <stdint.h>

#define BTOK 16384
#define DM   512
#define DFF  2048
#define NE   8
#define NPAIR (BTOK*2)
#define MAXT 288          // max 128-row tiles total (balanced: ~264)
#define TPXMAX 36         // ceil(MAXT/8): per-XCD tile chunk upper bound

typedef short s16x8 __attribute__((ext_vector_type(8)));   // 8 bf16 in 4 VGPRs
typedef float f32x4 __attribute__((ext_vector_type(4)));

// fp32 -> bf16 RNE (inputs finite)
__device__ __forceinline__ uint16_t f2b(float f) {
  uint32_t u = __float_as_uint(f);
  u += 0x7fff + ((u >> 16) & 1);
  return (uint16_t)(u >> 16);
}

// async global->LDS, 16B per lane; lds ptr must be wave-uniform base (HW adds lane*16)
__device__ __forceinline__ void g2l16(const void* gp, void* lp) {
  __builtin_amdgcn_global_load_lds(
      (__attribute__((address_space(1))) void*)(void*)gp,
      (__attribute__((address_space(3))) void*)lp, 16, 0, 0);
}

// ---------- transpose+convert, VECTORIZED 16B stores ----------
// z<8 -> W1 [D][DFF]->[DFF][D], z>=8 -> W2 [DFF][D]->[D][DFF]
__global__ void k_tr(const float* __restrict__ w1, const float* __restrict__ w2,
                     uint16_t* __restrict__ w1t, uint16_t* __restrict__ w2t) {
  __shared__ float t[32][33];
  int z = blockIdx.z, bx = blockIdx.x;
  int R, C, c0, r0;
  const float* src;
  uint16_t* dst;
  if (z < 8) { R = DM; C = DFF; c0 = (bx & 63) * 32; r0 = (bx >> 6) * 32;
               src = w1 + (size_t)z * R * C; dst = w1t + (size_t)z * R * C; }
  else       { R = DFF; C = DM; c0 = (bx & 15) * 32; r0 = (bx >> 4) * 32;
               src = w2 + (size_t)(z - 8) * R * C; dst = w2t + (size_t)(z - 8) * R * C; }
  int tx = threadIdx.x, ty = threadIdx.y;       // 32 x 8
#pragma unroll
  for (int j = 0; j < 4; j++)
    t[ty + j * 8][tx] = src[(size_t)(r0 + ty + j * 8) * C + c0 + tx];
  __syncthreads();
  int tid = ty * 32 + tx;
  int oc = tid >> 3, ch = tid & 7;              // output row oc (= src col), 16B chunk ch
  if (ch < 4) {
    uint16_t v[8];
#pragma unroll
    for (int k = 0; k < 8; k++) v[k] = f2b(t[ch * 8 + k][oc]);
    *(s16x8*)(dst + (size_t)(c0 + oc) * R + r0 + ch * 8) = *(s16x8*)v;
  }
}

// ---- gate + x->bf16: wave-per-token x16, wg in registers, LDS histogram; then convert block's x slab ----
__global__ __launch_bounds__(256) void k_route(const float* __restrict__ x,
                                               const float* __restrict__ wg,
                                               int* __restrict__ counts,
                                               int* __restrict__ tk_e, float* __restrict__ tk_w,
                                               uint16_t* __restrict__ xb) {
  __shared__ int hist[NE];
  int tid = threadIdx.x, lane = tid & 63, wave = tid >> 6;
  if (tid < NE) hist[tid] = 0;
  __syncthreads();

  float wv[8][8];
#pragma unroll
  for (int j = 0; j < 8; j++) {
    const float4* wr = (const float4*)(wg + (size_t)(j * 64 + lane) * NE);
    float4 a = wr[0], b = wr[1];
    wv[j][0] = a.x; wv[j][1] = a.y; wv[j][2] = a.z; wv[j][3] = a.w;
    wv[j][4] = b.x; wv[j][5] = b.y; wv[j][6] = b.z; wv[j][7] = b.w;
  }

  int tok0 = blockIdx.x * 64 + wave * 16;
  for (int tt = 0; tt < 16; tt++) {
    int tok = tok0 + tt;
    const float* xr = x + (size_t)tok * DM;
    float xv[8];
#pragma unroll
    for (int j = 0; j < 8; j++) xv[j] = xr[j * 64 + lane];
    float acc[NE];
#pragma unroll
    for (int e = 0; e < NE; e++) acc[e] = 0.f;
#pragma unroll
    for (int j = 0; j < 8; j++)
#pragma unroll
      for (int e = 0; e < NE; e++) acc[e] += xv[j] * wv[j][e];
#pragma unroll
    for (int e = 0; e < NE; e++) {
#pragma unroll
      for (int off = 32; off > 0; off >>= 1) acc[e] += __shfl_xor(acc[e], off, 64);
    }
    if (lane == 0) {
      float mx = acc[0];
      for (int e = 1; e < NE; e++) mx = fmaxf(mx, acc[e]);
      float p[NE], s = 0.f;
      for (int e = 0; e < NE; e++) { p[e] = __expf(acc[e] - mx); s += p[e]; }
      float inv = 1.f / s;
      int e0 = 0; float v0 = p[0];
      for (int e = 1; e < NE; e++) if (p[e] > v0) { v0 = p[e]; e0 = e; }  // strict > = top_k tiebreak
      int e1 = -1; float v1 = -1.f;
      for (int e = 0; e < NE; e++) if (e != e0 && p[e] > v1) { v1 = p[e]; e1 = e; }
      tk_e[tok * 2]     = e0; tk_w[tok * 2]     = v0 * inv;
      tk_e[tok * 2 + 1] = e1; tk_w[tok * 2 + 1] = v1 * inv;
      atomicAdd(&hist[e0], 1);
      atomicAdd(&hist[e1], 1);
    }
  }
  // convert this block's 64-token slab (L2-hot) to bf16
  const float* xs = x + (size_t)blockIdx.x * 32768;
  uint16_t* xd = xb + (size_t)blockIdx.x * 32768;
#pragma unroll
  for (int i = 0; i < 16; i++) {
    int o = i * 2048 + tid * 8;
    float4 a = *(const float4*)(xs + o);
    float4 b = *(const float4*)(xs + o + 4);
    uint16_t v[8] = {f2b(a.x), f2b(a.y), f2b(a.z), f2b(a.w),
                     f2b(b.x), f2b(b.y), f2b(b.z), f2b(b.w)};
    *(s16x8*)(xd + o) = *(s16x8*)v;
  }
  __syncthreads();
  if (tid < NE) atomicAdd(&counts[tid], hist[tid]);
}

// ---------------- prefix sums + 128-row tile map (parallelized) ----------------
__global__ void k_setup(const int* __restrict__ counts, int* __restrict__ offsets,
                        int* __restrict__ trB, int* __restrict__ texp, int* __restrict__ ntB) {
  __shared__ int soff[NE + 1], ts[NE + 1];
  int tid = threadIdx.x;
  if (tid == 0) {
    int off = 0;
    for (int e = 0; e < NE; e++) { soff[e] = off; offsets[e] = off; off += counts[e]; }
    soff[NE] = off; offsets[NE] = off;
    int nt = 0;
    for (int e = 0; e < NE; e++) { ts[e] = nt; nt += (counts[e] + 127) >> 7; }
    ts[NE] = nt; *ntB = nt;
  }
  __syncthreads();
  if (tid < NE) {
    int e = tid, base = ts[e], o = soff[e];
    int n = ts[e + 1] - ts[e];
    for (int i = 0; i < n; i++) { trB[base + i] = o + i * 128; texp[base + i] = e; }
  }
}

// ------- build compact slot lists + inverse map -------
__global__ __launch_bounds__(256) void k_build(const int* __restrict__ tk_e, const float* __restrict__ tk_w,
                                               const int* __restrict__ offsets, int* __restrict__ cursors,
                                               int* __restrict__ tok_of, float* __restrict__ w_of,
                                               int* __restrict__ inv) {
  __shared__ int lcnt[NE], lbase[NE];
  int tid = threadIdx.x;
  int i = blockIdx.x * 256 + tid;
  if (tid < NE) lcnt[tid] = 0;
  __syncthreads();
  int e = tk_e[i];
  int local = atomicAdd(&lcnt[e], 1);
  __syncthreads();
  if (tid < NE) lbase[tid] = atomicAdd(&cursors[tid], lcnt[tid]);
  __syncthreads();
  int slot = offsets[e] + lbase[e] + local;
  tok_of[slot] = i >> 1;
  w_of[slot] = tk_w[i];
  inv[i] = slot;
}

// =====================================================================================
// Pipelined GEMM core (round-6 passing, unchanged): 128x256 tile, 4 waves (2x2),
// wave tile 64x128, acc[4][8], BK=32, 3-deep LDS ring (72KB) -> 2 blocks/CU, counted
// vmcnt (VM6 steady, never 0 mid-loop), conflict-free granule swizzle (PMC=0).
// XCD-chunked block map (T1): id&7 = XCD (HW round-robin); each XCD owns a contiguous
// tile chunk and iterates all n0 of a tile consecutively -> A-slab + weight panels
// L2-resident per XCD.
// Round-7 lesson: atomicAdd-fused combine cost +25-30us on gemm2 (16.7M L2 RMWs at
// the tail) — reverted to y32 stores + separate k_combine.
// =====================================================================================

#define LDS16(off) (*(const s16x8*)((const char*)smem + (off)))
#define VM6 asm volatile("s_waitcnt vmcnt(6)" ::: "memory")
#define VM0 asm volatile("s_waitcnt vmcnt(0)" ::: "memory")
#define NOVM do{}while(0)
#define NOSTG do{}while(0)
#define MFMA16 __builtin_amdgcn_mfma_f32_16x16x32_bf16
#define BSTR 24576

#define DS0_P(bb) do{ \
  bf0 = LDS16(offB0 + (bb)*BSTR); bf1 = LDS16(offB1 + (bb)*BSTR); \
  bf2 = LDS16(offB2 + (bb)*BSTR); bf3 = LDS16(offB3 + (bb)*BSTR); \
  bf4 = LDS16(offB4 + (bb)*BSTR); bf5 = LDS16(offB5 + (bb)*BSTR); \
  bf6 = LDS16(offB6 + (bb)*BSTR); bf7 = LDS16(offB7 + (bb)*BSTR); \
  af0 = LDS16(offA0 + (bb)*BSTR); af1 = LDS16(offA1 + (bb)*BSTR); }while(0)
#define DS1_P(bb) do{ \
  af2 = LDS16(offA2 + (bb)*BSTR); af3 = LDS16(offA3 + (bb)*BSTR); }while(0)
#define SA_P(bb) do{ \
  g2l16(gA0, (char*)smem + (bb)*BSTR + wave*1024); \
  g2l16(gA1, (char*)smem + (bb)*BSTR + 4096 + wave*1024); \
  gA0 += 32; gA1 += 32; }while(0)
#define SB_P(bb) do{ \
  g2l16(gB0, (char*)smem + (bb)*BSTR + 8192 + wave*1024); \
  g2l16(gB1, (char*)smem + (bb)*BSTR + 12288 + wave*1024); \
  g2l16(gB2, (char*)smem + (bb)*BSTR + 16384 + wave*1024); \
  g2l16(gB3, (char*)smem + (bb)*BSTR + 20480 + wave*1024); \
  gB0 += 32; gB1 += 32; gB2 += 32; gB3 += 32; }while(0)
#define MM16A do{ \
  __builtin_amdgcn_s_setprio(1); \
  acc[0][0] = MFMA16(af0, bf0, acc[0][0], 0, 0, 0); \
  acc[1][0] = MFMA16(af1, bf0, acc[1][0], 0, 0, 0); \
  acc[0][1] = MFMA16(af0, bf1, acc[0][1], 0, 0, 0); \
  acc[1][1] = MFMA16(af1, bf1, acc[1][1], 0, 0, 0); \
  acc[0][2] = MFMA16(af0, bf2, acc[0][2], 0, 0, 0); \
  acc[1][2] = MFMA16(af1, bf2, acc[1][2], 0, 0, 0); \
  acc[0][3] = MFMA16(af0, bf3, acc[0][3], 0, 0, 0); \
  acc[1][3] = MFMA16(af1, bf3, acc[1][3], 0, 0, 0); \
  acc[0][4] = MFMA16(af0, bf4, acc[0][4], 0, 0, 0); \
  acc[1][4] = MFMA16(af1, bf4, acc[1][4], 0, 0, 0); \
  acc[0][5] = MFMA16(af0, bf5, acc[0][5], 0, 0, 0); \
  acc[1][5] = MFMA16(af1, bf5, acc[1][5], 0, 0, 0); \
  acc[0][6] = MFMA16(af0, bf6, acc[0][6], 0, 0, 0); \
  acc[1][6] = MFMA16(af1, bf6, acc[1][6], 0, 0, 0); \
  acc[0][7] = MFMA16(af0, bf7, acc[0][7], 0, 0, 0); \
  acc[1][7] = MFMA16(af1, bf7, acc[1][7], 0, 0, 0); \
  __builtin_amdgcn_s_setprio(0); }while(0)
#define MM16B do{ \
  __builtin_amdgcn_s_setprio(1); \
  acc[2][0] = MFMA16(af2, bf0, acc[2][0], 0, 0, 0); \
  acc[3][0] = MFMA16(af3, bf0, acc[3][0], 0, 0, 0); \
  acc[2][1] = MFMA16(af2, bf1, acc[2][1], 0, 0, 0); \
  acc[3][1] = MFMA16(af3, bf1, acc[3][1], 0, 0, 0); \
  acc[2][2] = MFMA16(af2, bf2, acc[2][2], 0, 0, 0); \
  acc[3][2] = MFMA16(af3, bf2, acc[3][2], 0, 0, 0); \
  acc[2][3] = MFMA16(af2, bf3, acc[2][3], 0, 0, 0); \
  acc[3][3] = MFMA16(af3, bf3, acc[3][3], 0, 0, 0); \
  acc[2][4] = MFMA16(af2, bf4, acc[2][4], 0, 0, 0); \
  acc[3][4] = MFMA16(af3, bf4, acc[3][4], 0, 0, 0); \
  acc[2][5] = MFMA16(af2, bf5, acc[2][5], 0, 0, 0); \
  acc[3][5] = MFMA16(af3, bf5, acc[3][5], 0, 0, 0); \
  acc[2][6] = MFMA16(af2, bf6, acc[2][6], 0, 0, 0); \
  acc[3][6] = MFMA16(af3, bf6, acc[3][6], 0, 0, 0); \
  acc[2][7] = MFMA16(af2, bf7, acc[2][7], 0, 0, 0); \
  acc[3][7] = MFMA16(af3, bf7, acc[3][7], 0, 0, 0); \
  __builtin_amdgcn_s_setprio(0); }while(0)
#define TILEP(bb, SA, SB, VMX) do{ \
  DS0_P(bb); SA; \
  __builtin_amdgcn_s_barrier(); \
  asm volatile("s_waitcnt lgkmcnt(0)" ::: "memory"); \
  MM16A; \
  __builtin_amdgcn_s_barrier(); \
  DS1_P(bb); SB; \
  __builtin_amdgcn_s_barrier(); \
  asm volatile("s_waitcnt lgkmcnt(0)" ::: "memory"); \
  MM16B; \
  VMX; \
  __builtin_amdgcn_s_barrier(); }while(0)

// common per-thread geometry (4 waves, 256 threads)
#define GEOM_SETUP \
  int tid = threadIdx.x, lane = tid & 63, wave = tid >> 6; \
  int wm = wave >> 1, wn = wave & 1; \
  int l15 = lane & 15, l4 = lane >> 4; \
  int offA0, offA1, offA2, offA3; \
  int offB0, offB1, offB2, offB3, offB4, offB5, offB6, offB7; \
  { int r; \
    r = wm*64 + 0*16 + l15; offA0 = r*64 + ((l4 ^ ((r>>1)&3)) << 4); \
    r = wm*64 + 1*16 + l15; offA1 = r*64 + ((l4 ^ ((r>>1)&3)) << 4); \
    r = wm*64 + 2*16 + l15; offA2 = r*64 + ((l4 ^ ((r>>1)&3)) << 4); \
    r = wm*64 + 3*16 + l15; offA3 = r*64 + ((l4 ^ ((r>>1)&3)) << 4); \
    r = wn*128 + 0*16 + l15; offB0 = 8192 + r*64 + ((l4 ^ ((r>>1)&3)) << 4); \
    r = wn*128 + 1*16 + l15; offB1 = 8192 + r*64 + ((l4 ^ ((r>>1)&3)) << 4); \
    r = wn*128 + 2*16 + l15; offB2 = 8192 + r*64 + ((l4 ^ ((r>>1)&3)) << 4); \
    r = wn*128 + 3*16 + l15; offB3 = 8192 + r*64 + ((l4 ^ ((r>>1)&3)) << 4); \
    r = wn*128 + 4*16 + l15; offB4 = 8192 + r*64 + ((l4 ^ ((r>>1)&3)) << 4); \
    r = wn*128 + 5*16 + l15; offB5 = 8192 + r*64 + ((l4 ^ ((r>>1)&3)) << 4); \
    r = wn*128 + 6*16 + l15; offB6 = 8192 + r*64 + ((l4 ^ ((r>>1)&3)) << 4); \
    r = wn*128 + 7*16 + l15; offB7 = 8192 + r*64 + ((l4 ^ ((r>>1)&3)) << 4); \
  } \
  int rp = tid >> 2, cp = (tid & 3) ^ ((rp >> 1) & 3);  /* stage: row rp(+64k), slot tid&3 */

#define ACC_INIT \
  f32x4 acc[4][8]; \
  _Pragma("unroll") for (int m = 0; m < 4; m++) \
  _Pragma("unroll") for (int n = 0; n < 8; n++) \
  _Pragma("unroll") for (int i = 0; i < 4; i++) acc[m][n][i] = 0.f; \
  s16x8 af0, af1, af2, af3, bf0, bf1, bf2, bf3, bf4, bf5, bf6, bf7;

// ---------- GEMM1: h[slot][DFF] = relu(x[tok] @ W1[e] + b1[e]); K=512, NT=16 ----------
__global__ __launch_bounds__(256, 2) void k_gemm1(
    const uint16_t* __restrict__ xb, const uint16_t* __restrict__ w1t,
    const float* __restrict__ b1,
    const int* __restrict__ tok_of, const int* __restrict__ offsets,
    const int* __restrict__ trB, const int* __restrict__ texp, const int* __restrict__ ntB,
    uint16_t* __restrict__ h) {
  __shared__ __align__(16) uint16_t smem[36864];   // 72KB: 3 bufs x (A 8KB + B 16KB)
  int id = blockIdx.x;
  int nt = *ntB, tpx = (nt + 7) >> 3;
  int x = id & 7, q = id >> 3, j = q >> 3;
  if (j >= tpx) return;
  int tile = x * tpx + j;
  if (tile >= nt) return;
  int n0 = (q & 7) * 256;
  int e = texp[tile], row0 = trB[tile], end = offsets[e + 1];
  GEOM_SETUP;

  const uint16_t *gA0, *gA1, *gB0, *gB1, *gB2, *gB3;
  { int s0 = row0 + rp;      if (s0 >= end) s0 = end - 1;
    int s1 = row0 + rp + 64; if (s1 >= end) s1 = end - 1;
    gA0 = xb + (size_t)tok_of[s0] * DM + cp * 8;
    gA1 = xb + (size_t)tok_of[s1] * DM + cp * 8; }
  { const uint16_t* wb = w1t + (size_t)e * DFF * DM;
    gB0 = wb + (size_t)(n0 + rp +   0) * DM + cp * 8;
    gB1 = wb + (size_t)(n0 + rp +  64) * DM + cp * 8;
    gB2 = wb + (size_t)(n0 + rp + 128) * DM + cp * 8;
    gB3 = wb + (size_t)(n0 + rp + 192) * DM + cp * 8; }

  ACC_INIT;

  SA_P(0); SB_P(0); SA_P(1); SB_P(1);
  VM6;
  __builtin_amdgcn_s_barrier();

#pragma unroll 1
  for (int g = 0; g < 4; ++g) {                    // tiles 0..11 (NT=16)
    TILEP(0, SA_P(2), SB_P(2), VM6);
    TILEP(1, SA_P(0), SB_P(0), VM6);
    TILEP(2, SA_P(1), SB_P(1), VM6);
  }
  TILEP(0, SA_P(2), SB_P(2), VM6);                 // tile 12 stages 14
  TILEP(1, SA_P(0), SB_P(0), VM6);                 // tile 13 stages 15
  TILEP(2, NOSTG, NOSTG, VM0);                     // tile 14
  TILEP(0, NOSTG, NOSTG, NOVM);                    // tile 15

  // epilogue: bias+relu -> bf16, per-wave LDS repack (row stride 272B: 16B-aligned, bank-spread)
  {
    float bv[8];
#pragma unroll
    for (int n = 0; n < 8; n++) bv[n] = b1[(size_t)e * DFF + n0 + wn * 128 + n * 16 + l15];
    char* wrg = (char*)smem + wave * 4608;
    int rr = lane >> 2, cb = lane & 3;
#pragma unroll
    for (int m = 0; m < 4; m++) {
#pragma unroll
      for (int n = 0; n < 8; n++)
#pragma unroll
        for (int i = 0; i < 4; i++) {
          float v = fmaxf(acc[m][n][i] + bv[n], 0.f);
          *(uint16_t*)(wrg + (l4 * 4 + i) * 272 + (n * 16 + l15) * 2) = f2b(v);
        }
      int gr = row0 + wm * 64 + m * 16 + rr;
      const char* src = wrg + rr * 272 + cb * 64;
      if (gr < end) {
        uint16_t* dst = h + (size_t)gr * DFF + n0 + wn * 128 + cb * 32;
        *(s16x8*)(dst +  0) = *(const s16x8*)(src +  0);
        *(s16x8*)(dst +  8) = *(const s16x8*)(src + 16);
        *(s16x8*)(dst + 16) = *(const s16x8*)(src + 32);
        *(s16x8*)(dst + 24) = *(const s16x8*)(src + 48);
      }
    }
  }
}

// ---------- GEMM2: y[slot] = w_of[slot]*(h[slot] @ W2[e] + b2[e]); K=2048, NT=64 ----------
__global__ __launch_bounds__(256, 2) void k_gemm2(
    const uint16_t* __restrict__ h, const uint16_t* __restrict__ w2t,
    const float* __restrict__ b2, const float* __restrict__ w_of,
    const int* __restrict__ offsets,
    const int* __restrict__ trB, const int* __restrict__ texp, const int* __restrict__ ntB,
    float* __restrict__ y32) {
  __shared__ __align__(16) uint16_t smem[36864];   // 72KB: 3 bufs x (A 8KB + B 16KB)
  int id = blockIdx.x;
  int nt = *ntB, tpx = (nt + 7) >> 3;
  int x = id & 7, q = id >> 3, j = q >> 1;
  if (j >= tpx) return;
  int tile = x * tpx + j;
  if (tile >= nt) return;
  int n0 = (q & 1) * 256;
  int e = texp[tile], row0 = trB[tile], end = offsets[e + 1];
  GEOM_SETUP;

  const uint16_t *gA0, *gA1, *gB0, *gB1, *gB2, *gB3;
  { int s0 = row0 + rp;      if (s0 >= end) s0 = end - 1;
    int s1 = row0 + rp + 64; if (s1 >= end) s1 = end - 1;
    gA0 = h + (size_t)s0 * DFF + cp * 8;
    gA1 = h + (size_t)s1 * DFF + cp * 8; }
  { const uint16_t* wb = w2t + (size_t)e * DM * DFF;
    gB0 = wb + (size_t)(n0 + rp +   0) * DFF + cp * 8;
    gB1 = wb + (size_t)(n0 + rp +  64) * DFF + cp * 8;
    gB2 = wb + (size_t)(n0 + rp + 128) * DFF + cp * 8;
    gB3 = wb + (size_t)(n0 + rp + 192) * DFF + cp * 8; }

  ACC_INIT;

  SA_P(0); SB_P(0); SA_P(1); SB_P(1);
  VM6;
  __builtin_amdgcn_s_barrier();

#pragma unroll 1
  for (int g = 0; g < 20; ++g) {                   // tiles 0..59 (NT=64)
    TILEP(0, SA_P(2), SB_P(2), VM6);
    TILEP(1, SA_P(0), SB_P(0), VM6);
    TILEP(2, SA_P(1), SB_P(1), VM6);
  }
  TILEP(0, SA_P(2), SB_P(2), VM6);                 // tile 60 stages 62
  TILEP(1, SA_P(0), SB_P(0), VM6);                 // tile 61 stages 63
  TILEP(2, NOSTG, NOSTG, VM0);                     // tile 62
  TILEP(0, NOSTG, NOSTG, NOVM);                    // tile 63

  // epilogue: weighted bias add, direct fp32 stores (16-lane 64B runs)
  {
    float bv[8];
#pragma unroll
    for (int n = 0; n < 8; n++) bv[n] = b2[(size_t)e * DM + n0 + wn * 128 + n * 16 + l15];
#pragma unroll
    for (int m = 0; m < 4; m++)
#pragma unroll
      for (int i = 0; i < 4; i++) {
        int slot = row0 + wm * 64 + m * 16 + l4 * 4 + i;
        if (slot < end) {
          float wgt = w_of[slot];
          size_t base = (size_t)slot * DM + n0 + wn * 128 + l15;
#pragma unroll
          for (int n = 0; n < 8; n++) y32[base + n * 16] = wgt * (acc[m][n][i] + bv[n]);
        }
      }
  }
}

// ---------------- combine: out[tok] = y[slot0] + y[slot1] (weights pre-applied) ----------------
__global__ __launch_bounds__(256) void k_combine(const float* __restrict__ y32,
                                                 const int* __restrict__ inv,
                                                 float* __restrict__ out) {
  int tid = threadIdx.x;
  int tok = blockIdx.x * 2 + (tid >> 7);
  int c4 = (tid & 127) * 4;
  int s0 = inv[tok * 2], s1 = inv[tok * 2 + 1];
  const float4 a = *(const float4*)(y32 + (size_t)s0 * DM + c4);
  const float4 b = *(const float4*)(y32 + (size_t)s1 * DM + c4);
  *(float4*)(out + (size_t)tok * DM + c4) = make_float4(a.x + b.x, a.y + b.y, a.z + b.z, a.w + b.w);
}

extern "C" void kernel_launch(void* const* d_in, const int* in_sizes, int n_in,
                              void* d_out, int out_size, void* d_ws, size_t ws_size,
                              hipStream_t stream) {
  const float* x  = (const float*)d_in[0];
  const float* wg = (const float*)d_in[1];
  const float* w1 = (const float*)d_in[2];
  const float* b1 = (const float*)d_in[3];
  const float* w2 = (const float*)d_in[4];
  const float* b2 = (const float*)d_in[5];
  float* out = (float*)d_out;

  char* ws = (char*)d_ws;
  const size_t MB = 1024 * 1024;
  uint16_t* xb   = (uint16_t*)ws;                  // [0,16) MB
  uint16_t* w1t  = (uint16_t*)(ws + 16 * MB);      // [16,32) MB  [E][DFF][DM]
  uint16_t* w2t  = (uint16_t*)(ws + 32 * MB);      // [32,48) MB  [E][DM][DFF]
  uint16_t* hbuf = (uint16_t*)(ws + 48 * MB);      // [48,176) MB [NPAIR][DFF]
  int* ctrl = (int*)(ws + 176 * MB);               // [176,177) MB
  int*   counts  = ctrl;                 // 0..8
  int*   cursors = ctrl + 8;             // 8..16
  int*   offsets = ctrl + 16;            // 16..25
  int*   ntB     = ctrl + 32;            // 32
  int*   trB     = ctrl + 64;            // 64..384 (320)
  int*   texp    = ctrl + 384;           // 384..704 (320)
  int*   tk_e    = ctrl + 1024;
  float* tk_w    = (float*)(ctrl + 1024 + 32768);
  int*   tok_of  = ctrl + 1024 + 2 * 32768;
  float* w_of    = (float*)(ctrl + 1024 + 3 * 32768);
  int*   inv     = ctrl + 1024 + 4 * 32768;
  float* y32     = (float*)(ws + 177 * MB);        // [177,241) MB fp32 [NPAIR][DM]

  hipMemsetAsync(counts, 0, 16 * sizeof(int), stream);

  k_route<<<BTOK / 64, 256, 0, stream>>>(x, wg, counts, tk_e, tk_w, xb);
  k_tr<<<dim3(1024, 1, 16), dim3(32, 8), 0, stream>>>(w1, w2, w1t, w2t);
  k_setup<<<1, 64, 0, stream>>>(counts, offsets, trB, texp, ntB);
  k_build<<<NPAIR / 256, 256, 0, stream>>>(tk_e, tk_w, offsets, cursors, tok_of, w_of, inv);
  k_gemm1<<<8 * TPXMAX * 8, 256, 0, stream>>>(xb, w1t, b1, tok_of, offsets,
                                              trB, texp, ntB, hbuf);
  k_gemm2<<<8 * TPXMAX * 2, 256, 0, stream>>>(hbuf, w2t, b2, w_of, offsets,
                                              trB, texp, ntB, y32);
  k_combine<<<BTOK / 2, 256, 0, stream>>>(y32, inv, out);
}

// Round 9
// 369.810 us; speedup vs baseline: 1.0904x; 1.0360x over previous
//
#include <hip/hip_runtime.h>
#include <stdint.h>

#define BTOK 16384
#define DM   512
#define DFF  2048
#define NE   8
#define NPAIR (BTOK*2)
#define MAXT 288          // max 128-row tiles total (balanced: ~264)
#define TPXMAX 36         // ceil(MAXT/8): per-XCD tile chunk upper bound

typedef short s16x8 __attribute__((ext_vector_type(8)));   // 8 bf16 in 4 VGPRs
typedef float f32x4 __attribute__((ext_vector_type(4)));

// fp32 -> bf16 RNE (inputs finite)
__device__ __forceinline__ uint16_t f2b(float f) {
  uint32_t u = __float_as_uint(f);
  u += 0x7fff + ((u >> 16) & 1);
  return (uint16_t)(u >> 16);
}

// async global->LDS, 16B per lane; lds ptr must be wave-uniform base (HW adds lane*16)
__device__ __forceinline__ void g2l16(const void* gp, void* lp) {
  __builtin_amdgcn_global_load_lds(
      (__attribute__((address_space(1))) void*)(void*)gp,
      (__attribute__((address_space(3))) void*)lp, 16, 0, 0);
}

// =====================================================================================
// k_prep: FUSED route + weight-transpose (independent work pools, one dispatch).
// Blocks [0,256): gate + x->bf16 (route). Blocks [256, 256+16384): W1/W2
// transpose+convert with 16B vector stores. Overlaps the two serial passes
// (~45us serial -> ~max(18,27)us) and removes one launch gap.
// =====================================================================================
__global__ __launch_bounds__(256) void k_prep(
    const float* __restrict__ x, const float* __restrict__ wg,
    int* __restrict__ counts, int* __restrict__ tk_e, float* __restrict__ tk_w,
    uint16_t* __restrict__ xb,
    const float* __restrict__ w1, const float* __restrict__ w2,
    uint16_t* __restrict__ w1t, uint16_t* __restrict__ w2t) {
  __shared__ float t[32][33];
  __shared__ int hist[NE];
  int tid = threadIdx.x;

  if (blockIdx.x >= 256) {
    // ---------------- transpose part ----------------
    int fid = blockIdx.x - 256;
    int bx = fid & 1023, z = fid >> 10;
    int R, C, c0, r0;
    const float* src;
    uint16_t* dst;
    if (z < 8) { R = DM; C = DFF; c0 = (bx & 63) * 32; r0 = (bx >> 6) * 32;
                 src = w1 + (size_t)z * R * C; dst = w1t + (size_t)z * R * C; }
    else       { R = DFF; C = DM; c0 = (bx & 15) * 32; r0 = (bx >> 4) * 32;
                 src = w2 + (size_t)(z - 8) * R * C; dst = w2t + (size_t)(z - 8) * R * C; }
    int tx = tid & 31, ty = tid >> 5;           // 32 x 8
#pragma unroll
    for (int j = 0; j < 4; j++)
      t[ty + j * 8][tx] = src[(size_t)(r0 + ty + j * 8) * C + c0 + tx];
    __syncthreads();
    int oc = tid >> 3, ch = tid & 7;            // output row oc (= src col), 16B chunk ch
    if (ch < 4) {
      uint16_t v[8];
#pragma unroll
      for (int k = 0; k < 8; k++) v[k] = f2b(t[ch * 8 + k][oc]);
      *(s16x8*)(dst + (size_t)(c0 + oc) * R + r0 + ch * 8) = *(s16x8*)v;
    }
    return;
  }

  // ---------------- route part ----------------
  int bid = blockIdx.x;
  int lane = tid & 63, wave = tid >> 6;
  if (tid < NE) hist[tid] = 0;
  __syncthreads();

  float wv[8][8];
#pragma unroll
  for (int j = 0; j < 8; j++) {
    const float4* wr = (const float4*)(wg + (size_t)(j * 64 + lane) * NE);
    float4 a = wr[0], b = wr[1];
    wv[j][0] = a.x; wv[j][1] = a.y; wv[j][2] = a.z; wv[j][3] = a.w;
    wv[j][4] = b.x; wv[j][5] = b.y; wv[j][6] = b.z; wv[j][7] = b.w;
  }

  int tok0 = bid * 64 + wave * 16;
  for (int tt = 0; tt < 16; tt++) {
    int tok = tok0 + tt;
    const float* xr = x + (size_t)tok * DM;
    float xv[8];
#pragma unroll
    for (int j = 0; j < 8; j++) xv[j] = xr[j * 64 + lane];
    float acc[NE];
#pragma unroll
    for (int e = 0; e < NE; e++) acc[e] = 0.f;
#pragma unroll
    for (int j = 0; j < 8; j++)
#pragma unroll
      for (int e = 0; e < NE; e++) acc[e] += xv[j] * wv[j][e];
#pragma unroll
    for (int e = 0; e < NE; e++) {
#pragma unroll
      for (int off = 32; off > 0; off >>= 1) acc[e] += __shfl_xor(acc[e], off, 64);
    }
    if (lane == 0) {
      float mx = acc[0];
      for (int e = 1; e < NE; e++) mx = fmaxf(mx, acc[e]);
      float p[NE], s = 0.f;
      for (int e = 0; e < NE; e++) { p[e] = __expf(acc[e] - mx); s += p[e]; }
      float inv = 1.f / s;
      int e0 = 0; float v0 = p[0];
      for (int e = 1; e < NE; e++) if (p[e] > v0) { v0 = p[e]; e0 = e; }  // strict > = top_k tiebreak
      int e1 = -1; float v1 = -1.f;
      for (int e = 0; e < NE; e++) if (e != e0 && p[e] > v1) { v1 = p[e]; e1 = e; }
      tk_e[tok * 2]     = e0; tk_w[tok * 2]     = v0 * inv;
      tk_e[tok * 2 + 1] = e1; tk_w[tok * 2 + 1] = v1 * inv;
      atomicAdd(&hist[e0], 1);
      atomicAdd(&hist[e1], 1);
    }
  }
  // convert this block's 64-token slab (L2-hot) to bf16
  const float* xs = x + (size_t)bid * 32768;
  uint16_t* xd = xb + (size_t)bid * 32768;
#pragma unroll
  for (int i = 0; i < 16; i++) {
    int o = i * 2048 + tid * 8;
    float4 a = *(const float4*)(xs + o);
    float4 b = *(const float4*)(xs + o + 4);
    uint16_t v[8] = {f2b(a.x), f2b(a.y), f2b(a.z), f2b(a.w),
                     f2b(b.x), f2b(b.y), f2b(b.z), f2b(b.w)};
    *(s16x8*)(xd + o) = *(s16x8*)v;
  }
  __syncthreads();
  if (tid < NE) atomicAdd(&counts[tid], hist[tid]);
}

// ---------------- prefix sums + 128-row tile map (parallelized) ----------------
__global__ void k_setup(const int* __restrict__ counts, int* __restrict__ offsets,
                        int* __restrict__ trB, int* __restrict__ texp, int* __restrict__ ntB) {
  __shared__ int soff[NE + 1], ts[NE + 1];
  int tid = threadIdx.x;
  if (tid == 0) {
    int off = 0;
    for (int e = 0; e < NE; e++) { soff[e] = off; offsets[e] = off; off += counts[e]; }
    soff[NE] = off; offsets[NE] = off;
    int nt = 0;
    for (int e = 0; e < NE; e++) { ts[e] = nt; nt += (counts[e] + 127) >> 7; }
    ts[NE] = nt; *ntB = nt;
  }
  __syncthreads();
  if (tid < NE) {
    int e = tid, base = ts[e], o = soff[e];
    int n = ts[e + 1] - ts[e];
    for (int i = 0; i < n; i++) { trB[base + i] = o + i * 128; texp[base + i] = e; }
  }
}

// ------- build compact slot lists + inverse map -------
__global__ __launch_bounds__(256) void k_build(const int* __restrict__ tk_e, const float* __restrict__ tk_w,
                                               const int* __restrict__ offsets, int* __restrict__ cursors,
                                               int* __restrict__ tok_of, float* __restrict__ w_of,
                                               int* __restrict__ inv) {
  __shared__ int lcnt[NE], lbase[NE];
  int tid = threadIdx.x;
  int i = blockIdx.x * 256 + tid;
  if (tid < NE) lcnt[tid] = 0;
  __syncthreads();
  int e = tk_e[i];
  int local = atomicAdd(&lcnt[e], 1);
  __syncthreads();
  if (tid < NE) lbase[tid] = atomicAdd(&cursors[tid], lcnt[tid]);
  __syncthreads();
  int slot = offsets[e] + lbase[e] + local;
  tok_of[slot] = i >> 1;
  w_of[slot] = tk_w[i];
  inv[i] = slot;
}

// =====================================================================================
// Pipelined GEMM core (round-6/8 passing, unchanged): 128x256 tile, 4 waves (2x2),
// wave tile 64x128, acc[4][8], BK=32, 3-deep LDS ring (72KB) -> 2 blocks/CU, counted
// vmcnt (VM6 steady, never 0 mid-loop), conflict-free granule swizzle (PMC=0).
// XCD-chunked block map (T1): id&7 = XCD; each XCD owns a contiguous tile chunk and
// iterates all n0 of a tile consecutively (FETCH 139->61MB confirmed round 8).
// Round-7 lesson: atomicAdd-fused combine cost +25-30us — keep y32 + k_combine.
// =====================================================================================

#define LDS16(off) (*(const s16x8*)((const char*)smem + (off)))
#define VM6 asm volatile("s_waitcnt vmcnt(6)" ::: "memory")
#define VM0 asm volatile("s_waitcnt vmcnt(0)" ::: "memory")
#define NOVM do{}while(0)
#define NOSTG do{}while(0)
#define MFMA16 __builtin_amdgcn_mfma_f32_16x16x32_bf16
#define BSTR 24576

#define DS0_P(bb) do{ \
  bf0 = LDS16(offB0 + (bb)*BSTR); bf1 = LDS16(offB1 + (bb)*BSTR); \
  bf2 = LDS16(offB2 + (bb)*BSTR); bf3 = LDS16(offB3 + (bb)*BSTR); \
  bf4 = LDS16(offB4 + (bb)*BSTR); bf5 = LDS16(offB5 + (bb)*BSTR); \
  bf6 = LDS16(offB6 + (bb)*BSTR); bf7 = LDS16(offB7 + (bb)*BSTR); \
  af0 = LDS16(offA0 + (bb)*BSTR); af1 = LDS16(offA1 + (bb)*BSTR); }while(0)
#define DS1_P(bb) do{ \
  af2 = LDS16(offA2 + (bb)*BSTR); af3 = LDS16(offA3 + (bb)*BSTR); }while(0)
#define SA_P(bb) do{ \
  g2l16(gA0, (char*)smem + (bb)*BSTR + wave*1024); \
  g2l16(gA1, (char*)smem + (bb)*BSTR + 4096 + wave*1024); \
  gA0 += 32; gA1 += 32; }while(0)
#define SB_P(bb) do{ \
  g2l16(gB0, (char*)smem + (bb)*BSTR + 8192 + wave*1024); \
  g2l16(gB1, (char*)smem + (bb)*BSTR + 12288 + wave*1024); \
  g2l16(gB2, (char*)smem + (bb)*BSTR + 16384 + wave*1024); \
  g2l16(gB3, (char*)smem + (bb)*BSTR + 20480 + wave*1024); \
  gB0 += 32; gB1 += 32; gB2 += 32; gB3 += 32; }while(0)
#define MM16A do{ \
  __builtin_amdgcn_s_setprio(1); \
  acc[0][0] = MFMA16(af0, bf0, acc[0][0], 0, 0, 0); \
  acc[1][0] = MFMA16(af1, bf0, acc[1][0], 0, 0, 0); \
  acc[0][1] = MFMA16(af0, bf1, acc[0][1], 0, 0, 0); \
  acc[1][1] = MFMA16(af1, bf1, acc[1][1], 0, 0, 0); \
  acc[0][2] = MFMA16(af0, bf2, acc[0][2], 0, 0, 0); \
  acc[1][2] = MFMA16(af1, bf2, acc[1][2], 0, 0, 0); \
  acc[0][3] = MFMA16(af0, bf3, acc[0][3], 0, 0, 0); \
  acc[1][3] = MFMA16(af1, bf3, acc[1][3], 0, 0, 0); \
  acc[0][4] = MFMA16(af0, bf4, acc[0][4], 0, 0, 0); \
  acc[1][4] = MFMA16(af1, bf4, acc[1][4], 0, 0, 0); \
  acc[0][5] = MFMA16(af0, bf5, acc[0][5], 0, 0, 0); \
  acc[1][5] = MFMA16(af1, bf5, acc[1][5], 0, 0, 0); \
  acc[0][6] = MFMA16(af0, bf6, acc[0][6], 0, 0, 0); \
  acc[1][6] = MFMA16(af1, bf6, acc[1][6], 0, 0, 0); \
  acc[0][7] = MFMA16(af0, bf7, acc[0][7], 0, 0, 0); \
  acc[1][7] = MFMA16(af1, bf7, acc[1][7], 0, 0, 0); \
  __builtin_amdgcn_s_setprio(0); }while(0)
#define MM16B do{ \
  __builtin_amdgcn_s_setprio(1); \
  acc[2][0] = MFMA16(af2, bf0, acc[2][0], 0, 0, 0); \
  acc[3][0] = MFMA16(af3, bf0, acc[3][0], 0, 0, 0); \
  acc[2][1] = MFMA16(af2, bf1, acc[2][1], 0, 0, 0); \
  acc[3][1] = MFMA16(af3, bf1, acc[3][1], 0, 0, 0); \
  acc[2][2] = MFMA16(af2, bf2, acc[2][2], 0, 0, 0); \
  acc[3][2] = MFMA16(af3, bf2, acc[3][2], 0, 0, 0); \
  acc[2][3] = MFMA16(af2, bf3, acc[2][3], 0, 0, 0); \
  acc[3][3] = MFMA16(af3, bf3, acc[3][3], 0, 0, 0); \
  acc[2][4] = MFMA16(af2, bf4, acc[2][4], 0, 0, 0); \
  acc[3][4] = MFMA16(af3, bf4, acc[3][4], 0, 0, 0); \
  acc[2][5] = MFMA16(af2, bf5, acc[2][5], 0, 0, 0); \
  acc[3][5] = MFMA16(af3, bf5, acc[3][5], 0, 0, 0); \
  acc[2][6] = MFMA16(af2, bf6, acc[2][6], 0, 0, 0); \
  acc[3][6] = MFMA16(af3, bf6, acc[3][6], 0, 0, 0); \
  acc[2][7] = MFMA16(af2, bf7, acc[2][7], 0, 0, 0); \
  acc[3][7] = MFMA16(af3, bf7, acc[3][7], 0, 0, 0); \
  __builtin_amdgcn_s_setprio(0); }while(0)
#define TILEP(bb, SA, SB, VMX) do{ \
  DS0_P(bb); SA; \
  __builtin_amdgcn_s_barrier(); \
  asm volatile("s_waitcnt lgkmcnt(0)" ::: "memory"); \
  MM16A; \
  __builtin_amdgcn_s_barrier(); \
  DS1_P(bb); SB; \
  __builtin_amdgcn_s_barrier(); \
  asm volatile("s_waitcnt lgkmcnt(0)" ::: "memory"); \
  MM16B; \
  VMX; \
  __builtin_amdgcn_s_barrier(); }while(0)

// common per-thread geometry (4 waves, 256 threads)
#define GEOM_SETUP \
  int tid = threadIdx.x, lane = tid & 63, wave = tid >> 6; \
  int wm = wave >> 1, wn = wave & 1; \
  int l15 = lane & 15, l4 = lane >> 4; \
  int offA0, offA1, offA2, offA3; \
  int offB0, offB1, offB2, offB3, offB4, offB5, offB6, offB7; \
  { int r; \
    r = wm*64 + 0*16 + l15; offA0 = r*64 + ((l4 ^ ((r>>1)&3)) << 4); \
    r = wm*64 + 1*16 + l15; offA1 = r*64 + ((l4 ^ ((r>>1)&3)) << 4); \
    r = wm*64 + 2*16 + l15; offA2 = r*64 + ((l4 ^ ((r>>1)&3)) << 4); \
    r = wm*64 + 3*16 + l15; offA3 = r*64 + ((l4 ^ ((r>>1)&3)) << 4); \
    r = wn*128 + 0*16 + l15; offB0 = 8192 + r*64 + ((l4 ^ ((r>>1)&3)) << 4); \
    r = wn*128 + 1*16 + l15; offB1 = 8192 + r*64 + ((l4 ^ ((r>>1)&3)) << 4); \
    r = wn*128 + 2*16 + l15; offB2 = 8192 + r*64 + ((l4 ^ ((r>>1)&3)) << 4); \
    r = wn*128 + 3*16 + l15; offB3 = 8192 + r*64 + ((l4 ^ ((r>>1)&3)) << 4); \
    r = wn*128 + 4*16 + l15; offB4 = 8192 + r*64 + ((l4 ^ ((r>>1)&3)) << 4); \
    r = wn*128 + 5*16 + l15; offB5 = 8192 + r*64 + ((l4 ^ ((r>>1)&3)) << 4); \
    r = wn*128 + 6*16 + l15; offB6 = 8192 + r*64 + ((l4 ^ ((r>>1)&3)) << 4); \
    r = wn*128 + 7*16 + l15; offB7 = 8192 + r*64 + ((l4 ^ ((r>>1)&3)) << 4); \
  } \
  int rp = tid >> 2, cp = (tid & 3) ^ ((rp >> 1) & 3);  /* stage: row rp(+64k), slot tid&3 */

#define ACC_INIT \
  f32x4 acc[4][8]; \
  _Pragma("unroll") for (int m = 0; m < 4; m++) \
  _Pragma("unroll") for (int n = 0; n < 8; n++) \
  _Pragma("unroll") for (int i = 0; i < 4; i++) acc[m][n][i] = 0.f; \
  s16x8 af0, af1, af2, af3, bf0, bf1, bf2, bf3, bf4, bf5, bf6, bf7;

// ---------- GEMM1: h[slot][DFF] = relu(x[tok] @ W1[e] + b1[e]); K=512, NT=16 ----------
__global__ __launch_bounds__(256, 2) void k_gemm1(
    const uint16_t* __restrict__ xb, const uint16_t* __restrict__ w1t,
    const float* __restrict__ b1,
    const int* __restrict__ tok_of, const int* __restrict__ offsets,
    const int* __restrict__ trB, const int* __restrict__ texp, const int* __restrict__ ntB,
    uint16_t* __restrict__ h) {
  __shared__ __align__(16) uint16_t smem[36864];   // 72KB: 3 bufs x (A 8KB + B 16KB)
  int id = blockIdx.x;
  int nt = *ntB, tpx = (nt + 7) >> 3;
  int x = id & 7, q = id >> 3, j = q >> 3;
  if (j >= tpx) return;
  int tile = x * tpx + j;
  if (tile >= nt) return;
  int n0 = (q & 7) * 256;
  int e = texp[tile], row0 = trB[tile], end = offsets[e + 1];
  GEOM_SETUP;

  const uint16_t *gA0, *gA1, *gB0, *gB1, *gB2, *gB3;
  { int s0 = row0 + rp;      if (s0 >= end) s0 = end - 1;
    int s1 = row0 + rp + 64; if (s1 >= end) s1 = end - 1;
    gA0 = xb + (size_t)tok_of[s0] * DM + cp * 8;
    gA1 = xb + (size_t)tok_of[s1] * DM + cp * 8; }
  { const uint16_t* wb = w1t + (size_t)e * DFF * DM;
    gB0 = wb + (size_t)(n0 + rp +   0) * DM + cp * 8;
    gB1 = wb + (size_t)(n0 + rp +  64) * DM + cp * 8;
    gB2 = wb + (size_t)(n0 + rp + 128) * DM + cp * 8;
    gB3 = wb + (size_t)(n0 + rp + 192) * DM + cp * 8; }

  ACC_INIT;

  SA_P(0); SB_P(0); SA_P(1); SB_P(1);
  VM6;
  __builtin_amdgcn_s_barrier();

#pragma unroll 1
  for (int g = 0; g < 4; ++g) {                    // tiles 0..11 (NT=16)
    TILEP(0, SA_P(2), SB_P(2), VM6);
    TILEP(1, SA_P(0), SB_P(0), VM6);
    TILEP(2, SA_P(1), SB_P(1), VM6);
  }
  TILEP(0, SA_P(2), SB_P(2), VM6);                 // tile 12 stages 14
  TILEP(1, SA_P(0), SB_P(0), VM6);                 // tile 13 stages 15
  TILEP(2, NOSTG, NOSTG, VM0);                     // tile 14
  TILEP(0, NOSTG, NOSTG, NOVM);                    // tile 15

  // epilogue: bias+relu -> bf16, per-wave LDS repack (row stride 272B: 16B-aligned, bank-spread)
  {
    float bv[8];
#pragma unroll
    for (int n = 0; n < 8; n++) bv[n] = b1[(size_t)e * DFF + n0 + wn * 128 + n * 16 + l15];
    char* wrg = (char*)smem + wave * 4608;
    int rr = lane >> 2, cb = lane & 3;
#pragma unroll
    for (int m = 0; m < 4; m++) {
#pragma unroll
      for (int n = 0; n < 8; n++)
#pragma unroll
        for (int i = 0; i < 4; i++) {
          float v = fmaxf(acc[m][n][i] + bv[n], 0.f);
          *(uint16_t*)(wrg + (l4 * 4 + i) * 272 + (n * 16 + l15) * 2) = f2b(v);
        }
      int gr = row0 + wm * 64 + m * 16 + rr;
      const char* src = wrg + rr * 272 + cb * 64;
      if (gr < end) {
        uint16_t* dst = h + (size_t)gr * DFF + n0 + wn * 128 + cb * 32;
        *(s16x8*)(dst +  0) = *(const s16x8*)(src +  0);
        *(s16x8*)(dst +  8) = *(const s16x8*)(src + 16);
        *(s16x8*)(dst + 16) = *(const s16x8*)(src + 32);
        *(s16x8*)(dst + 24) = *(const s16x8*)(src + 48);
      }
    }
  }
}

// ---------- GEMM2: y[slot] = w_of[slot]*(h[slot] @ W2[e] + b2[e]); K=2048, NT=64 ----------
__global__ __launch_bounds__(256, 2) void k_gemm2(
    const uint16_t* __restrict__ h, const uint16_t* __restrict__ w2t,
    const float* __restrict__ b2, const float* __restrict__ w_of,
    const int* __restrict__ offsets,
    const int* __restrict__ trB, const int* __restrict__ texp, const int* __restrict__ ntB,
    float* __restrict__ y32) {
  __shared__ __align__(16) uint16_t smem[36864];   // 72KB: 3 bufs x (A 8KB + B 16KB)
  int id = blockIdx.x;
  int nt = *ntB, tpx = (nt + 7) >> 3;
  int x = id & 7, q = id >> 3, j = q >> 1;
  if (j >= tpx) return;
  int tile = x * tpx + j;
  if (tile >= nt) return;
  int n0 = (q & 1) * 256;
  int e = texp[tile], row0 = trB[tile], end = offsets[e + 1];
  GEOM_SETUP;

  const uint16_t *gA0, *gA1, *gB0, *gB1, *gB2, *gB3;
  { int s0 = row0 + rp;      if (s0 >= end) s0 = end - 1;
    int s1 = row0 + rp + 64; if (s1 >= end) s1 = end - 1;
    gA0 = h + (size_t)s0 * DFF + cp * 8;
    gA1 = h + (size_t)s1 * DFF + cp * 8; }
  { const uint16_t* wb = w2t + (size_t)e * DM * DFF;
    gB0 = wb + (size_t)(n0 + rp +   0) * DFF + cp * 8;
    gB1 = wb + (size_t)(n0 + rp +  64) * DFF + cp * 8;
    gB2 = wb + (size_t)(n0 + rp + 128) * DFF + cp * 8;
    gB3 = wb + (size_t)(n0 + rp + 192) * DFF + cp * 8; }

  ACC_INIT;

  SA_P(0); SB_P(0); SA_P(1); SB_P(1);
  VM6;
  __builtin_amdgcn_s_barrier();

#pragma unroll 1
  for (int g = 0; g < 20; ++g) {                   // tiles 0..59 (NT=64)
    TILEP(0, SA_P(2), SB_P(2), VM6);
    TILEP(1, SA_P(0), SB_P(0), VM6);
    TILEP(2, SA_P(1), SB_P(1), VM6);
  }
  TILEP(0, SA_P(2), SB_P(2), VM6);                 // tile 60 stages 62
  TILEP(1, SA_P(0), SB_P(0), VM6);                 // tile 61 stages 63
  TILEP(2, NOSTG, NOSTG, VM0);                     // tile 62
  TILEP(0, NOSTG, NOSTG, NOVM);                    // tile 63

  // epilogue: weighted bias add, direct fp32 stores (16-lane 64B runs)
  {
    float bv[8];
#pragma unroll
    for (int n = 0; n < 8; n++) bv[n] = b2[(size_t)e * DM + n0 + wn * 128 + n * 16 + l15];
#pragma unroll
    for (int m = 0; m < 4; m++)
#pragma unroll
      for (int i = 0; i < 4; i++) {
        int slot = row0 + wm * 64 + m * 16 + l4 * 4 + i;
        if (slot < end) {
          float wgt = w_of[slot];
          size_t base = (size_t)slot * DM + n0 + wn * 128 + l15;
#pragma unroll
          for (int n = 0; n < 8; n++) y32[base + n * 16] = wgt * (acc[m][n][i] + bv[n]);
        }
      }
  }
}

// ---------------- combine: out[tok] = y[slot0] + y[slot1] (weights pre-applied) ----------------
__global__ __launch_bounds__(256) void k_combine(const float* __restrict__ y32,
                                                 const int* __restrict__ inv,
                                                 float* __restrict__ out) {
  int tid = threadIdx.x;
  int tok = blockIdx.x * 2 + (tid >> 7);
  int c4 = (tid & 127) * 4;
  int s0 = inv[tok * 2], s1 = inv[tok * 2 + 1];
  const float4 a = *(const float4*)(y32 + (size_t)s0 * DM + c4);
  const float4 b = *(const float4*)(y32 + (size_t)s1 * DM + c4);
  *(float4*)(out + (size_t)tok * DM + c4) = make_float4(a.x + b.x, a.y + b.y, a.z + b.z, a.w + b.w);
}

extern "C" void kernel_launch(void* const* d_in, const int* in_sizes, int n_in,
                              void* d_out, int out_size, void* d_ws, size_t ws_size,
                              hipStream_t stream) {
  const float* x  = (const float*)d_in[0];
  const float* wg = (const float*)d_in[1];
  const float* w1 = (const float*)d_in[2];
  const float* b1 = (const float*)d_in[3];
  const float* w2 = (const float*)d_in[4];
  const float* b2 = (const float*)d_in[5];
  float* out = (float*)d_out;

  char* ws = (char*)d_ws;
  const size_t MB = 1024 * 1024;
  uint16_t* xb   = (uint16_t*)ws;                  // [0,16) MB
  uint16_t* w1t  = (uint16_t*)(ws + 16 * MB);      // [16,32) MB  [E][DFF][DM]
  uint16_t* w2t  = (uint16_t*)(ws + 32 * MB);      // [32,48) MB  [E][DM][DFF]
  uint16_t* hbuf = (uint16_t*)(ws + 48 * MB);      // [48,176) MB [NPAIR][DFF]
  int* ctrl = (int*)(ws + 176 * MB);               // [176,177) MB
  int*   counts  = ctrl;                 // 0..8
  int*   cursors = ctrl + 8;             // 8..16
  int*   offsets = ctrl + 16;            // 16..25
  int*   ntB     = ctrl + 32;            // 32
  int*   trB     = ctrl + 64;            // 64..384 (320)
  int*   texp    = ctrl + 384;           // 384..704 (320)
  int*   tk_e    = ctrl + 1024;
  float* tk_w    = (float*)(ctrl + 1024 + 32768);
  int*   tok_of  = ctrl + 1024 + 2 * 32768;
  float* w_of    = (float*)(ctrl + 1024 + 3 * 32768);
  int*   inv     = ctrl + 1024 + 4 * 32768;
  float* y32     = (float*)(ws + 177 * MB);        // [177,241) MB fp32 [NPAIR][DM]

  hipMemsetAsync(counts, 0, 16 * sizeof(int), stream);

  k_prep<<<256 + 16384, 256, 0, stream>>>(x, wg, counts, tk_e, tk_w, xb,
                                          w1, w2, w1t, w2t);
  k_setup<<<1, 64, 0, stream>>>(counts, offsets, trB, texp, ntB);
  k_build<<<NPAIR / 256, 256, 0, stream>>>(tk_e, tk_w, offsets, cursors, tok_of, w_of, inv);
  k_gemm1<<<8 * TPXMAX * 8, 256, 0, stream>>>(xb, w1t, b1, tok_of, offsets,
                                              trB, texp, ntB, hbuf);
  k_gemm2<<<8 * TPXMAX * 2, 256, 0, stream>>>(hbuf, w2t, b2, w_of, offsets,
                                              trB, texp, ntB, y32);
  k_combine<<<BTOK / 2, 256, 0, stream>>>(y32, inv, out);
}

// Round 10
// 365.914 us; speedup vs baseline: 1.1020x; 1.0106x over previous
//
#include <hip/hip_runtime.h>
#include <stdint.h>

#define BTOK 16384
#define DM   512
#define DFF  2048
#define NE   8
#define NPAIR (BTOK*2)
#define MAXT 288          // max 128-row tiles total (balanced: ~264)
#define TPXMAX 36         // ceil(MAXT/8): per-XCD tile chunk upper bound

typedef short s16x8 __attribute__((ext_vector_type(8)));   // 8 bf16 in 4 VGPRs
typedef float f32x4 __attribute__((ext_vector_type(4)));

// fp32 -> bf16 RNE (inputs finite)
__device__ __forceinline__ uint16_t f2b(float f) {
  uint32_t u = __float_as_uint(f);
  u += 0x7fff + ((u >> 16) & 1);
  return (uint16_t)(u >> 16);
}

// async global->LDS, 16B per lane; lds ptr must be wave-uniform base (HW adds lane*16)
__device__ __forceinline__ void g2l16(const void* gp, void* lp) {
  __builtin_amdgcn_global_load_lds(
      (__attribute__((address_space(1))) void*)(void*)gp,
      (__attribute__((address_space(3))) void*)lp, 16, 0, 0);
}

// =====================================================================================
// k_prep: FUSED route + weight-transpose (independent pools, one dispatch).
// Blocks [0,256): gate + x->bf16. Blocks [256, 256+16384): W1/W2 transpose+convert
// with 16B vector stores. (Round 9: 383->370us confirmed.)
// =====================================================================================
__global__ __launch_bounds__(256) void k_prep(
    const float* __restrict__ x, const float* __restrict__ wg,
    int* __restrict__ counts, int* __restrict__ tk_e, float* __restrict__ tk_w,
    uint16_t* __restrict__ xb,
    const float* __restrict__ w1, const float* __restrict__ w2,
    uint16_t* __restrict__ w1t, uint16_t* __restrict__ w2t) {
  __shared__ float t[32][33];
  __shared__ int hist[NE];
  int tid = threadIdx.x;

  if (blockIdx.x >= 256) {
    // ---------------- transpose part ----------------
    int fid = blockIdx.x - 256;
    int bx = fid & 1023, z = fid >> 10;
    int R, C, c0, r0;
    const float* src;
    uint16_t* dst;
    if (z < 8) { R = DM; C = DFF; c0 = (bx & 63) * 32; r0 = (bx >> 6) * 32;
                 src = w1 + (size_t)z * R * C; dst = w1t + (size_t)z * R * C; }
    else       { R = DFF; C = DM; c0 = (bx & 15) * 32; r0 = (bx >> 4) * 32;
                 src = w2 + (size_t)(z - 8) * R * C; dst = w2t + (size_t)(z - 8) * R * C; }
    int tx = tid & 31, ty = tid >> 5;           // 32 x 8
#pragma unroll
    for (int j = 0; j < 4; j++)
      t[ty + j * 8][tx] = src[(size_t)(r0 + ty + j * 8) * C + c0 + tx];
    __syncthreads();
    int oc = tid >> 3, ch = tid & 7;            // output row oc (= src col), 16B chunk ch
    if (ch < 4) {
      uint16_t v[8];
#pragma unroll
      for (int k = 0; k < 8; k++) v[k] = f2b(t[ch * 8 + k][oc]);
      *(s16x8*)(dst + (size_t)(c0 + oc) * R + r0 + ch * 8) = *(s16x8*)v;
    }
    return;
  }

  // ---------------- route part ----------------
  int bid = blockIdx.x;
  int lane = tid & 63, wave = tid >> 6;
  if (tid < NE) hist[tid] = 0;
  __syncthreads();

  float wv[8][8];
#pragma unroll
  for (int j = 0; j < 8; j++) {
    const float4* wr = (const float4*)(wg + (size_t)(j * 64 + lane) * NE);
    float4 a = wr[0], b = wr[1];
    wv[j][0] = a.x; wv[j][1] = a.y; wv[j][2] = a.z; wv[j][3] = a.w;
    wv[j][4] = b.x; wv[j][5] = b.y; wv[j][6] = b.z; wv[j][7] = b.w;
  }

  int tok0 = bid * 64 + wave * 16;
  for (int tt = 0; tt < 16; tt++) {
    int tok = tok0 + tt;
    const float* xr = x + (size_t)tok * DM;
    float xv[8];
#pragma unroll
    for (int j = 0; j < 8; j++) xv[j] = xr[j * 64 + lane];
    float acc[NE];
#pragma unroll
    for (int e = 0; e < NE; e++) acc[e] = 0.f;
#pragma unroll
    for (int j = 0; j < 8; j++)
#pragma unroll
      for (int e = 0; e < NE; e++) acc[e] += xv[j] * wv[j][e];
#pragma unroll
    for (int e = 0; e < NE; e++) {
#pragma unroll
      for (int off = 32; off > 0; off >>= 1) acc[e] += __shfl_xor(acc[e], off, 64);
    }
    if (lane == 0) {
      float mx = acc[0];
      for (int e = 1; e < NE; e++) mx = fmaxf(mx, acc[e]);
      float p[NE], s = 0.f;
      for (int e = 0; e < NE; e++) { p[e] = __expf(acc[e] - mx); s += p[e]; }
      float inv = 1.f / s;
      int e0 = 0; float v0 = p[0];
      for (int e = 1; e < NE; e++) if (p[e] > v0) { v0 = p[e]; e0 = e; }  // strict > = top_k tiebreak
      int e1 = -1; float v1 = -1.f;
      for (int e = 0; e < NE; e++) if (e != e0 && p[e] > v1) { v1 = p[e]; e1 = e; }
      tk_e[tok * 2]     = e0; tk_w[tok * 2]     = v0 * inv;
      tk_e[tok * 2 + 1] = e1; tk_w[tok * 2 + 1] = v1 * inv;
      atomicAdd(&hist[e0], 1);
      atomicAdd(&hist[e1], 1);
    }
  }
  // convert this block's 64-token slab (L2-hot) to bf16
  const float* xs = x + (size_t)bid * 32768;
  uint16_t* xd = xb + (size_t)bid * 32768;
#pragma unroll
  for (int i = 0; i < 16; i++) {
    int o = i * 2048 + tid * 8;
    float4 a = *(const float4*)(xs + o);
    float4 b = *(const float4*)(xs + o + 4);
    uint16_t v[8] = {f2b(a.x), f2b(a.y), f2b(a.z), f2b(a.w),
                     f2b(b.x), f2b(b.y), f2b(b.z), f2b(b.w)};
    *(s16x8*)(xd + o) = *(s16x8*)v;
  }
  __syncthreads();
  if (tid < NE) atomicAdd(&counts[tid], hist[tid]);
}

// ------- build compact slot lists (k_setup folded away: offsets derived from counts) -------
// tok_of[slot] now stores the PAIR index i (= tok*2 + k), so gemm2 can write y32 in
// token-pair order and combine becomes a pure streaming add (no inv indirection).
__global__ __launch_bounds__(256) void k_build(const int* __restrict__ tk_e, const float* __restrict__ tk_w,
                                               const int* __restrict__ counts, int* __restrict__ cursors,
                                               int* __restrict__ tok_of, float* __restrict__ w_of) {
  __shared__ int lcnt[NE], lbase[NE], soff[NE];
  int tid = threadIdx.x;
  int i = blockIdx.x * 256 + tid;
  if (tid < NE) {
    lcnt[tid] = 0;
    int off = 0;
    for (int e2 = 0; e2 < tid; e2++) off += counts[e2];   // 8-wide prefix from counts
    soff[tid] = off;
  }
  __syncthreads();
  int e = tk_e[i];
  int local = atomicAdd(&lcnt[e], 1);
  __syncthreads();
  if (tid < NE) lbase[tid] = atomicAdd(&cursors[tid], lcnt[tid]);
  __syncthreads();
  int slot = soff[e] + lbase[e] + local;
  tok_of[slot] = i;                 // pair index
  w_of[slot] = tk_w[i];
}

// =====================================================================================
// Pipelined GEMM core (round-6/8/9 passing, unchanged): 128x256 tile, 4 waves (2x2),
// wave tile 64x128, acc[4][8], BK=32, 3-deep LDS ring (72KB) -> 2 blocks/CU, counted
// vmcnt (VM6 steady, never 0 mid-loop), conflict-free granule swizzle (PMC=0).
// XCD-chunked block map (T1) confirmed: FETCH 139->61MB (round 8).
// NEW (round 10): tile map computed in-kernel from counts (k_setup dispatch removed).
// Expert lookup is an unrolled compare-select (rule #20: no runtime-indexed locals).
// =====================================================================================

#define LDS16(off) (*(const s16x8*)((const char*)smem + (off)))
#define VM6 asm volatile("s_waitcnt vmcnt(6)" ::: "memory")
#define VM0 asm volatile("s_waitcnt vmcnt(0)" ::: "memory")
#define NOVM do{}while(0)
#define NOSTG do{}while(0)
#define MFMA16 __builtin_amdgcn_mfma_f32_16x16x32_bf16
#define BSTR 24576

// tile map from counts: nt (total 128-row tiles); for tile t: e, row0, end.
#define TILEMAP_NT \
  int nt = 0; \
  _Pragma("unroll") for (int e2 = 0; e2 < NE; e2++) nt += (counts[e2] + 127) >> 7;
#define TILEMAP_FIND(tile) \
  int e = 0, row0 = 0, end = 0; \
  { int ntk = 0, off = 0; \
    _Pragma("unroll") for (int e2 = 0; e2 < NE; e2++) { \
      int c = counts[e2]; \
      if ((tile) >= ntk) { e = e2; row0 = off + ((tile) - ntk) * 128; end = off + c; } \
      ntk += (c + 127) >> 7; off += c; } }

#define DS0_P(bb) do{ \
  bf0 = LDS16(offB0 + (bb)*BSTR); bf1 = LDS16(offB1 + (bb)*BSTR); \
  bf2 = LDS16(offB2 + (bb)*BSTR); bf3 = LDS16(offB3 + (bb)*BSTR); \
  bf4 = LDS16(offB4 + (bb)*BSTR); bf5 = LDS16(offB5 + (bb)*BSTR); \
  bf6 = LDS16(offB6 + (bb)*BSTR); bf7 = LDS16(offB7 + (bb)*BSTR); \
  af0 = LDS16(offA0 + (bb)*BSTR); af1 = LDS16(offA1 + (bb)*BSTR); }while(0)
#define DS1_P(bb) do{ \
  af2 = LDS16(offA2 + (bb)*BSTR); af3 = LDS16(offA3 + (bb)*BSTR); }while(0)
#define SA_P(bb) do{ \
  g2l16(gA0, (char*)smem + (bb)*BSTR + wave*1024); \
  g2l16(gA1, (char*)smem + (bb)*BSTR + 4096 + wave*1024); \
  gA0 += 32; gA1 += 32; }while(0)
#define SB_P(bb) do{ \
  g2l16(gB0, (char*)smem + (bb)*BSTR + 8192 + wave*1024); \
  g2l16(gB1, (char*)smem + (bb)*BSTR + 12288 + wave*1024); \
  g2l16(gB2, (char*)smem + (bb)*BSTR + 16384 + wave*1024); \
  g2l16(gB3, (char*)smem + (bb)*BSTR + 20480 + wave*1024); \
  gB0 += 32; gB1 += 32; gB2 += 32; gB3 += 32; }while(0)
#define MM16A do{ \
  __builtin_amdgcn_s_setprio(1); \
  acc[0][0] = MFMA16(af0, bf0, acc[0][0], 0, 0, 0); \
  acc[1][0] = MFMA16(af1, bf0, acc[1][0], 0, 0, 0); \
  acc[0][1] = MFMA16(af0, bf1, acc[0][1], 0, 0, 0); \
  acc[1][1] = MFMA16(af1, bf1, acc[1][1], 0, 0, 0); \
  acc[0][2] = MFMA16(af0, bf2, acc[0][2], 0, 0, 0); \
  acc[1][2] = MFMA16(af1, bf2, acc[1][2], 0, 0, 0); \
  acc[0][3] = MFMA16(af0, bf3, acc[0][3], 0, 0, 0); \
  acc[1][3] = MFMA16(af1, bf3, acc[1][3], 0, 0, 0); \
  acc[0][4] = MFMA16(af0, bf4, acc[0][4], 0, 0, 0); \
  acc[1][4] = MFMA16(af1, bf4, acc[1][4], 0, 0, 0); \
  acc[0][5] = MFMA16(af0, bf5, acc[0][5], 0, 0, 0); \
  acc[1][5] = MFMA16(af1, bf5, acc[1][5], 0, 0, 0); \
  acc[0][6] = MFMA16(af0, bf6, acc[0][6], 0, 0, 0); \
  acc[1][6] = MFMA16(af1, bf6, acc[1][6], 0, 0, 0); \
  acc[0][7] = MFMA16(af0, bf7, acc[0][7], 0, 0, 0); \
  acc[1][7] = MFMA16(af1, bf7, acc[1][7], 0, 0, 0); \
  __builtin_amdgcn_s_setprio(0); }while(0)
#define MM16B do{ \
  __builtin_amdgcn_s_setprio(1); \
  acc[2][0] = MFMA16(af2, bf0, acc[2][0], 0, 0, 0); \
  acc[3][0] = MFMA16(af3, bf0, acc[3][0], 0, 0, 0); \
  acc[2][1] = MFMA16(af2, bf1, acc[2][1], 0, 0, 0); \
  acc[3][1] = MFMA16(af3, bf1, acc[3][1], 0, 0, 0); \
  acc[2][2] = MFMA16(af2, bf2, acc[2][2], 0, 0, 0); \
  acc[3][2] = MFMA16(af3, bf2, acc[3][2], 0, 0, 0); \
  acc[2][3] = MFMA16(af2, bf3, acc[2][3], 0, 0, 0); \
  acc[3][3] = MFMA16(af3, bf3, acc[3][3], 0, 0, 0); \
  acc[2][4] = MFMA16(af2, bf4, acc[2][4], 0, 0, 0); \
  acc[3][4] = MFMA16(af3, bf4, acc[3][4], 0, 0, 0); \
  acc[2][5] = MFMA16(af2, bf5, acc[2][5], 0, 0, 0); \
  acc[3][5] = MFMA16(af3, bf5, acc[3][5], 0, 0, 0); \
  acc[2][6] = MFMA16(af2, bf6, acc[2][6], 0, 0, 0); \
  acc[3][6] = MFMA16(af3, bf6, acc[3][6], 0, 0, 0); \
  acc[2][7] = MFMA16(af2, bf7, acc[2][7], 0, 0, 0); \
  acc[3][7] = MFMA16(af3, bf7, acc[3][7], 0, 0, 0); \
  __builtin_amdgcn_s_setprio(0); }while(0)
#define TILEP(bb, SA, SB, VMX) do{ \
  DS0_P(bb); SA; \
  __builtin_amdgcn_s_barrier(); \
  asm volatile("s_waitcnt lgkmcnt(0)" ::: "memory"); \
  MM16A; \
  __builtin_amdgcn_s_barrier(); \
  DS1_P(bb); SB; \
  __builtin_amdgcn_s_barrier(); \
  asm volatile("s_waitcnt lgkmcnt(0)" ::: "memory"); \
  MM16B; \
  VMX; \
  __builtin_amdgcn_s_barrier(); }while(0)

// common per-thread geometry (4 waves, 256 threads)
#define GEOM_SETUP \
  int tid = threadIdx.x, lane = tid & 63, wave = tid >> 6; \
  int wm = wave >> 1, wn = wave & 1; \
  int l15 = lane & 15, l4 = lane >> 4; \
  int offA0, offA1, offA2, offA3; \
  int offB0, offB1, offB2, offB3, offB4, offB5, offB6, offB7; \
  { int r; \
    r = wm*64 + 0*16 + l15; offA0 = r*64 + ((l4 ^ ((r>>1)&3)) << 4); \
    r = wm*64 + 1*16 + l15; offA1 = r*64 + ((l4 ^ ((r>>1)&3)) << 4); \
    r = wm*64 + 2*16 + l15; offA2 = r*64 + ((l4 ^ ((r>>1)&3)) << 4); \
    r = wm*64 + 3*16 + l15; offA3 = r*64 + ((l4 ^ ((r>>1)&3)) << 4); \
    r = wn*128 + 0*16 + l15; offB0 = 8192 + r*64 + ((l4 ^ ((r>>1)&3)) << 4); \
    r = wn*128 + 1*16 + l15; offB1 = 8192 + r*64 + ((l4 ^ ((r>>1)&3)) << 4); \
    r = wn*128 + 2*16 + l15; offB2 = 8192 + r*64 + ((l4 ^ ((r>>1)&3)) << 4); \
    r = wn*128 + 3*16 + l15; offB3 = 8192 + r*64 + ((l4 ^ ((r>>1)&3)) << 4); \
    r = wn*128 + 4*16 + l15; offB4 = 8192 + r*64 + ((l4 ^ ((r>>1)&3)) << 4); \
    r = wn*128 + 5*16 + l15; offB5 = 8192 + r*64 + ((l4 ^ ((r>>1)&3)) << 4); \
    r = wn*128 + 6*16 + l15; offB6 = 8192 + r*64 + ((l4 ^ ((r>>1)&3)) << 4); \
    r = wn*128 + 7*16 + l15; offB7 = 8192 + r*64 + ((l4 ^ ((r>>1)&3)) << 4); \
  } \
  int rp = tid >> 2, cp = (tid & 3) ^ ((rp >> 1) & 3);  /* stage: row rp(+64k), slot tid&3 */

#define ACC_INIT \
  f32x4 acc[4][8]; \
  _Pragma("unroll") for (int m = 0; m < 4; m++) \
  _Pragma("unroll") for (int n = 0; n < 8; n++) \
  _Pragma("unroll") for (int i = 0; i < 4; i++) acc[m][n][i] = 0.f; \
  s16x8 af0, af1, af2, af3, bf0, bf1, bf2, bf3, bf4, bf5, bf6, bf7;

// ---------- GEMM1: h[slot][DFF] = relu(x[tok] @ W1[e] + b1[e]); K=512, NT=16 ----------
__global__ __launch_bounds__(256, 2) void k_gemm1(
    const uint16_t* __restrict__ xb, const uint16_t* __restrict__ w1t,
    const float* __restrict__ b1,
    const int* __restrict__ tok_of, const int* __restrict__ counts,
    uint16_t* __restrict__ h) {
  __shared__ __align__(16) uint16_t smem[36864];   // 72KB: 3 bufs x (A 8KB + B 16KB)
  int id = blockIdx.x;
  TILEMAP_NT;
  int tpx = (nt + 7) >> 3;
  int x = id & 7, q = id >> 3, j = q >> 3;
  if (j >= tpx) return;
  int tile = x * tpx + j;
  if (tile >= nt) return;
  int n0 = (q & 7) * 256;
  TILEMAP_FIND(tile);
  GEOM_SETUP;

  const uint16_t *gA0, *gA1, *gB0, *gB1, *gB2, *gB3;
  { int s0 = row0 + rp;      if (s0 >= end) s0 = end - 1;
    int s1 = row0 + rp + 64; if (s1 >= end) s1 = end - 1;
    gA0 = xb + (size_t)(tok_of[s0] >> 1) * DM + cp * 8;
    gA1 = xb + (size_t)(tok_of[s1] >> 1) * DM + cp * 8; }
  { const uint16_t* wb = w1t + (size_t)e * DFF * DM;
    gB0 = wb + (size_t)(n0 + rp +   0) * DM + cp * 8;
    gB1 = wb + (size_t)(n0 + rp +  64) * DM + cp * 8;
    gB2 = wb + (size_t)(n0 + rp + 128) * DM + cp * 8;
    gB3 = wb + (size_t)(n0 + rp + 192) * DM + cp * 8; }

  ACC_INIT;

  SA_P(0); SB_P(0); SA_P(1); SB_P(1);
  VM6;
  __builtin_amdgcn_s_barrier();

#pragma unroll 1
  for (int g = 0; g < 4; ++g) {                    // tiles 0..11 (NT=16)
    TILEP(0, SA_P(2), SB_P(2), VM6);
    TILEP(1, SA_P(0), SB_P(0), VM6);
    TILEP(2, SA_P(1), SB_P(1), VM6);
  }
  TILEP(0, SA_P(2), SB_P(2), VM6);                 // tile 12 stages 14
  TILEP(1, SA_P(0), SB_P(0), VM6);                 // tile 13 stages 15
  TILEP(2, NOSTG, NOSTG, VM0);                     // tile 14
  TILEP(0, NOSTG, NOSTG, NOVM);                    // tile 15

  // epilogue: bias+relu -> bf16, per-wave LDS repack (row stride 272B: 16B-aligned, bank-spread)
  {
    float bv[8];
#pragma unroll
    for (int n = 0; n < 8; n++) bv[n] = b1[(size_t)e * DFF + n0 + wn * 128 + n * 16 + l15];
    char* wrg = (char*)smem + wave * 4608;
    int rr = lane >> 2, cb = lane & 3;
#pragma unroll
    for (int m = 0; m < 4; m++) {
#pragma unroll
      for (int n = 0; n < 8; n++)
#pragma unroll
        for (int i = 0; i < 4; i++) {
          float v = fmaxf(acc[m][n][i] + bv[n], 0.f);
          *(uint16_t*)(wrg + (l4 * 4 + i) * 272 + (n * 16 + l15) * 2) = f2b(v);
        }
      int gr = row0 + wm * 64 + m * 16 + rr;
      const char* src = wrg + rr * 272 + cb * 64;
      if (gr < end) {
        uint16_t* dst = h + (size_t)gr * DFF + n0 + wn * 128 + cb * 32;
        *(s16x8*)(dst +  0) = *(const s16x8*)(src +  0);
        *(s16x8*)(dst +  8) = *(const s16x8*)(src + 16);
        *(s16x8*)(dst + 16) = *(const s16x8*)(src + 32);
        *(s16x8*)(dst + 24) = *(const s16x8*)(src + 48);
      }
    }
  }
}

// ---------- GEMM2: y32[pair] = w_of[slot]*(h[slot] @ W2[e] + b2[e]); K=2048, NT=64 ----------
// Output indexed by PAIR (tok*2+k) so combine is a streaming add of adjacent rows.
__global__ __launch_bounds__(256, 2) void k_gemm2(
    const uint16_t* __restrict__ h, const uint16_t* __restrict__ w2t,
    const float* __restrict__ b2, const float* __restrict__ w_of,
    const int* __restrict__ tok_of, const int* __restrict__ counts,
    float* __restrict__ y32) {
  __shared__ __align__(16) uint16_t smem[36864];   // 72KB: 3 bufs x (A 8KB + B 16KB)
  int id = blockIdx.x;
  TILEMAP_NT;
  int tpx = (nt + 7) >> 3;
  int x = id & 7, q = id >> 3, j = q >> 1;
  if (j >= tpx) return;
  int tile = x * tpx + j;
  if (tile >= nt) return;
  int n0 = (q & 1) * 256;
  TILEMAP_FIND(tile);
  GEOM_SETUP;

  const uint16_t *gA0, *gA1, *gB0, *gB1, *gB2, *gB3;
  { int s0 = row0 + rp;      if (s0 >= end) s0 = end - 1;
    int s1 = row0 + rp + 64; if (s1 >= end) s1 = end - 1;
    gA0 = h + (size_t)s0 * DFF + cp * 8;
    gA1 = h + (size_t)s1 * DFF + cp * 8; }
  { const uint16_t* wb = w2t + (size_t)e * DM * DFF;
    gB0 = wb + (size_t)(n0 + rp +   0) * DFF + cp * 8;
    gB1 = wb + (size_t)(n0 + rp +  64) * DFF + cp * 8;
    gB2 = wb + (size_t)(n0 + rp + 128) * DFF + cp * 8;
    gB3 = wb + (size_t)(n0 + rp + 192) * DFF + cp * 8; }

  ACC_INIT;

  SA_P(0); SB_P(0); SA_P(1); SB_P(1);
  VM6;
  __builtin_amdgcn_s_barrier();

#pragma unroll 1
  for (int g = 0; g < 20; ++g) {                   // tiles 0..59 (NT=64)
    TILEP(0, SA_P(2), SB_P(2), VM6);
    TILEP(1, SA_P(0), SB_P(0), VM6);
    TILEP(2, SA_P(1), SB_P(1), VM6);
  }
  TILEP(0, SA_P(2), SB_P(2), VM6);                 // tile 60 stages 62
  TILEP(1, SA_P(0), SB_P(0), VM6);                 // tile 61 stages 63
  TILEP(2, NOSTG, NOSTG, VM0);                     // tile 62
  TILEP(0, NOSTG, NOSTG, NOVM);                    // tile 63

  // epilogue: weighted bias add, fp32 stores into pair-indexed y32 (16-lane 64B runs)
  {
    float bv[8];
#pragma unroll
    for (int n = 0; n < 8; n++) bv[n] = b2[(size_t)e * DM + n0 + wn * 128 + n * 16 + l15];
#pragma unroll
    for (int m = 0; m < 4; m++)
#pragma unroll
      for (int i = 0; i < 4; i++) {
        int slot = row0 + wm * 64 + m * 16 + l4 * 4 + i;
        if (slot < end) {
          float wgt = w_of[slot];
          int pr = tok_of[slot];                   // pair index = tok*2 + k
          size_t base = (size_t)pr * DM + n0 + wn * 128 + l15;
#pragma unroll
          for (int n = 0; n < 8; n++) y32[base + n * 16] = wgt * (acc[m][n][i] + bv[n]);
        }
      }
  }
}

// ---------------- combine: out[tok] = y32[2tok] + y32[2tok+1] (streaming, no indirection) ----------------
__global__ __launch_bounds__(256) void k_combine(const float* __restrict__ y32,
                                                 float* __restrict__ out) {
  int tid = threadIdx.x;
  int tok = blockIdx.x * 2 + (tid >> 7);
  int c4 = (tid & 127) * 4;
  const float4 a = *(const float4*)(y32 + (size_t)(tok * 2)     * DM + c4);
  const float4 b = *(const float4*)(y32 + (size_t)(tok * 2 + 1) * DM + c4);
  *(float4*)(out + (size_t)tok * DM + c4) = make_float4(a.x + b.x, a.y + b.y, a.z + b.z, a.w + b.w);
}

extern "C" void kernel_launch(void* const* d_in, const int* in_sizes, int n_in,
                              void* d_out, int out_size, void* d_ws, size_t ws_size,
                              hipStream_t stream) {
  const float* x  = (const float*)d_in[0];
  const float* wg = (const float*)d_in[1];
  const float* w1 = (const float*)d_in[2];
  const float* b1 = (const float*)d_in[3];
  const float* w2 = (const float*)d_in[4];
  const float* b2 = (const float*)d_in[5];
  float* out = (float*)d_out;

  char* ws = (char*)d_ws;
  const size_t MB = 1024 * 1024;
  uint16_t* xb   = (uint16_t*)ws;                  // [0,16) MB
  uint16_t* w1t  = (uint16_t*)(ws + 16 * MB);      // [16,32) MB  [E][DFF][DM]
  uint16_t* w2t  = (uint16_t*)(ws + 32 * MB);      // [32,48) MB  [E][DM][DFF]
  uint16_t* hbuf = (uint16_t*)(ws + 48 * MB);      // [48,176) MB [NPAIR][DFF]
  int* ctrl = (int*)(ws + 176 * MB);               // [176,177) MB
  int*   counts  = ctrl;                 // 0..8
  int*   cursors = ctrl + 8;             // 8..16
  int*   tk_e    = ctrl + 1024;
  float* tk_w    = (float*)(ctrl + 1024 + 32768);
  int*   tok_of  = ctrl + 1024 + 2 * 32768;
  float* w_of    = (float*)(ctrl + 1024 + 3 * 32768);
  float* y32     = (float*)(ws + 177 * MB);        // [177,241) MB fp32 [NPAIR][DM]

  hipMemsetAsync(counts, 0, 16 * sizeof(int), stream);

  k_prep<<<256 + 16384, 256, 0, stream>>>(x, wg, counts, tk_e, tk_w, xb,
                                          w1, w2, w1t, w2t);
  k_build<<<NPAIR / 256, 256, 0, stream>>>(tk_e, tk_w, counts, cursors, tok_of, w_of);
  k_gemm1<<<8 * TPXMAX * 8, 256, 0, stream>>>(xb, w1t, b1, tok_of, counts, hbuf);
  k_gemm2<<<8 * TPXMAX * 2, 256, 0, stream>>>(hbuf, w2t, b2, w_of, tok_of, counts, y32);
  k_combine<<<BTOK / 2, 256, 0, stream>>>(y32, out);
}

// Round 11
// 365.155 us; speedup vs baseline: 1.1043x; 1.0021x over previous
//
#include <hip/hip_runtime.h>
#include <stdint.h>

#define BTOK 16384
#define DM   512
#define DFF  2048
#define NE   8
#define NPAIR (BTOK*2)
#define MAXT 288          // max 128-row tiles total (balanced: ~264)
#define TPXMAX 36         // ceil(MAXT/8): per-XCD tile chunk upper bound

typedef short s16x8 __attribute__((ext_vector_type(8)));   // 8 bf16 in 4 VGPRs
typedef float f32x4 __attribute__((ext_vector_type(4)));

// fp32 -> bf16 RNE (inputs finite)
__device__ __forceinline__ uint16_t f2b(float f) {
  uint32_t u = __float_as_uint(f);
  u += 0x7fff + ((u >> 16) & 1);
  return (uint16_t)(u >> 16);
}

// async global->LDS, 16B per lane; lds ptr must be wave-uniform base (HW adds lane*16)
__device__ __forceinline__ void g2l16(const void* gp, void* lp) {
  __builtin_amdgcn_global_load_lds(
      (__attribute__((address_space(1))) void*)(void*)gp,
      (__attribute__((address_space(3))) void*)lp, 16, 0, 0);
}

// =====================================================================================
// k_prep: FUSED route + weight-transpose (independent pools, one dispatch).
// Blocks [0,256): gate + x->bf16. Blocks [256, 256+16384): W1/W2 transpose+convert
// with 16B vector stores. (Round 9: 383->370us confirmed.)
// =====================================================================================
__global__ __launch_bounds__(256) void k_prep(
    const float* __restrict__ x, const float* __restrict__ wg,
    int* __restrict__ counts, int* __restrict__ tk_e, float* __restrict__ tk_w,
    uint16_t* __restrict__ xb,
    const float* __restrict__ w1, const float* __restrict__ w2,
    uint16_t* __restrict__ w1t, uint16_t* __restrict__ w2t) {
  __shared__ float t[32][33];
  __shared__ int hist[NE];
  int tid = threadIdx.x;

  if (blockIdx.x >= 256) {
    // ---------------- transpose part ----------------
    int fid = blockIdx.x - 256;
    int bx = fid & 1023, z = fid >> 10;
    int R, C, c0, r0;
    const float* src;
    uint16_t* dst;
    if (z < 8) { R = DM; C = DFF; c0 = (bx & 63) * 32; r0 = (bx >> 6) * 32;
                 src = w1 + (size_t)z * R * C; dst = w1t + (size_t)z * R * C; }
    else       { R = DFF; C = DM; c0 = (bx & 15) * 32; r0 = (bx >> 4) * 32;
                 src = w2 + (size_t)(z - 8) * R * C; dst = w2t + (size_t)(z - 8) * R * C; }
    int tx = tid & 31, ty = tid >> 5;           // 32 x 8
#pragma unroll
    for (int j = 0; j < 4; j++)
      t[ty + j * 8][tx] = src[(size_t)(r0 + ty + j * 8) * C + c0 + tx];
    __syncthreads();
    int oc = tid >> 3, ch = tid & 7;            // output row oc (= src col), 16B chunk ch
    if (ch < 4) {
      uint16_t v[8];
#pragma unroll
      for (int k = 0; k < 8; k++) v[k] = f2b(t[ch * 8 + k][oc]);
      *(s16x8*)(dst + (size_t)(c0 + oc) * R + r0 + ch * 8) = *(s16x8*)v;
    }
    return;
  }

  // ---------------- route part ----------------
  int bid = blockIdx.x;
  int lane = tid & 63, wave = tid >> 6;
  if (tid < NE) hist[tid] = 0;
  __syncthreads();

  float wv[8][8];
#pragma unroll
  for (int j = 0; j < 8; j++) {
    const float4* wr = (const float4*)(wg + (size_t)(j * 64 + lane) * NE);
    float4 a = wr[0], b = wr[1];
    wv[j][0] = a.x; wv[j][1] = a.y; wv[j][2] = a.z; wv[j][3] = a.w;
    wv[j][4] = b.x; wv[j][5] = b.y; wv[j][6] = b.z; wv[j][7] = b.w;
  }

  int tok0 = bid * 64 + wave * 16;
  for (int tt = 0; tt < 16; tt++) {
    int tok = tok0 + tt;
    const float* xr = x + (size_t)tok * DM;
    float xv[8];
#pragma unroll
    for (int j = 0; j < 8; j++) xv[j] = xr[j * 64 + lane];
    float acc[NE];
#pragma unroll
    for (int e = 0; e < NE; e++) acc[e] = 0.f;
#pragma unroll
    for (int j = 0; j < 8; j++)
#pragma unroll
      for (int e = 0; e < NE; e++) acc[e] += xv[j] * wv[j][e];
#pragma unroll
    for (int e = 0; e < NE; e++) {
#pragma unroll
      for (int off = 32; off > 0; off >>= 1) acc[e] += __shfl_xor(acc[e], off, 64);
    }
    if (lane == 0) {
      float mx = acc[0];
      for (int e = 1; e < NE; e++) mx = fmaxf(mx, acc[e]);
      float p[NE], s = 0.f;
      for (int e = 0; e < NE; e++) { p[e] = __expf(acc[e] - mx); s += p[e]; }
      float inv = 1.f / s;
      int e0 = 0; float v0 = p[0];
      for (int e = 1; e < NE; e++) if (p[e] > v0) { v0 = p[e]; e0 = e; }  // strict > = top_k tiebreak
      int e1 = -1; float v1 = -1.f;
      for (int e = 0; e < NE; e++) if (e != e0 && p[e] > v1) { v1 = p[e]; e1 = e; }
      tk_e[tok * 2]     = e0; tk_w[tok * 2]     = v0 * inv;
      tk_e[tok * 2 + 1] = e1; tk_w[tok * 2 + 1] = v1 * inv;
      atomicAdd(&hist[e0], 1);
      atomicAdd(&hist[e1], 1);
    }
  }
  // convert this block's 64-token slab (L2-hot) to bf16
  const float* xs = x + (size_t)bid * 32768;
  uint16_t* xd = xb + (size_t)bid * 32768;
#pragma unroll
  for (int i = 0; i < 16; i++) {
    int o = i * 2048 + tid * 8;
    float4 a = *(const float4*)(xs + o);
    float4 b = *(const float4*)(xs + o + 4);
    uint16_t v[8] = {f2b(a.x), f2b(a.y), f2b(a.z), f2b(a.w),
                     f2b(b.x), f2b(b.y), f2b(b.z), f2b(b.w)};
    *(s16x8*)(xd + o) = *(s16x8*)v;
  }
  __syncthreads();
  if (tid < NE) atomicAdd(&counts[tid], hist[tid]);
}

// ------- build compact slot lists + (block 0) emit tile map / offsets -------
// tok_of[slot] stores the PAIR index i (= tok*2 + k): gemm2 writes y32 pair-indexed,
// combine is a pure streaming add (round 10 win, kept). Tile map precomputed HERE
// (round-10 lesson: computing it per-block in the GEMM preamble cost gemm1 +11us).
__global__ __launch_bounds__(256) void k_build(const int* __restrict__ tk_e, const float* __restrict__ tk_w,
                                               const int* __restrict__ counts, int* __restrict__ cursors,
                                               int* __restrict__ tok_of, float* __restrict__ w_of,
                                               int* __restrict__ offsets,
                                               int* __restrict__ trB, int* __restrict__ texp,
                                               int* __restrict__ ntB) {
  __shared__ int lcnt[NE], lbase[NE], soff[NE + 1];
  int tid = threadIdx.x;
  int i = blockIdx.x * 256 + tid;
  if (tid < NE) {
    lcnt[tid] = 0;
    int off = 0;
    for (int e2 = 0; e2 < tid; e2++) off += counts[e2];   // 8-wide prefix from counts
    soff[tid] = off;
  }
  __syncthreads();
  int e = tk_e[i];
  int local = atomicAdd(&lcnt[e], 1);
  __syncthreads();
  if (tid < NE) lbase[tid] = atomicAdd(&cursors[tid], lcnt[tid]);
  __syncthreads();
  int slot = soff[e] + lbase[e] + local;
  tok_of[slot] = i;                 // pair index
  w_of[slot] = tk_w[i];

  // block 0: emit offsets + 128-row tile map for the GEMMs (parallel over experts)
  if (blockIdx.x == 0) {
    if (tid < NE) {
      int base = 0;
#pragma unroll
      for (int e2 = 0; e2 < NE; e2++) if (e2 < tid) base += (counts[e2] + 127) >> 7;
      int o = soff[tid];
      int n = (counts[tid] + 127) >> 7;
      for (int k = 0; k < n; k++) { trB[base + k] = o + k * 128; texp[base + k] = tid; }
      offsets[tid] = o;
    }
    if (tid == 0) {
      int nt = 0, tot = 0;
#pragma unroll
      for (int e2 = 0; e2 < NE; e2++) { nt += (counts[e2] + 127) >> 7; tot += counts[e2]; }
      *ntB = nt;
      offsets[NE] = tot;
    }
  }
}

// =====================================================================================
// Pipelined GEMM core (round-9 passing form, bit-restored): 128x256 tile, 4 waves
// (2x2), wave tile 64x128, acc[4][8], BK=32, 3-deep LDS ring (72KB) -> 2 blocks/CU,
// counted vmcnt (VM6 steady, never 0 mid-loop), conflict-free granule swizzle (PMC=0).
// XCD-chunked block map (T1): FETCH 139->61MB confirmed (round 8).
// Round-10 lesson: in-preamble tilemap recompute cost gemm1 113.8->125us — the map is
// precomputed in k_build block 0 and read as 3 scalar loads, exactly as in round 9.
// =====================================================================================

#define LDS16(off) (*(const s16x8*)((const char*)smem + (off)))
#define VM6 asm volatile("s_waitcnt vmcnt(6)" ::: "memory")
#define VM0 asm volatile("s_waitcnt vmcnt(0)" ::: "memory")
#define NOVM do{}while(0)
#define NOSTG do{}while(0)
#define MFMA16 __builtin_amdgcn_mfma_f32_16x16x32_bf16
#define BSTR 24576

#define DS0_P(bb) do{ \
  bf0 = LDS16(offB0 + (bb)*BSTR); bf1 = LDS16(offB1 + (bb)*BSTR); \
  bf2 = LDS16(offB2 + (bb)*BSTR); bf3 = LDS16(offB3 + (bb)*BSTR); \
  bf4 = LDS16(offB4 + (bb)*BSTR); bf5 = LDS16(offB5 + (bb)*BSTR); \
  bf6 = LDS16(offB6 + (bb)*BSTR); bf7 = LDS16(offB7 + (bb)*BSTR); \
  af0 = LDS16(offA0 + (bb)*BSTR); af1 = LDS16(offA1 + (bb)*BSTR); }while(0)
#define DS1_P(bb) do{ \
  af2 = LDS16(offA2 + (bb)*BSTR); af3 = LDS16(offA3 + (bb)*BSTR); }while(0)
#define SA_P(bb) do{ \
  g2l16(gA0, (char*)smem + (bb)*BSTR + wave*1024); \
  g2l16(gA1, (char*)smem + (bb)*BSTR + 4096 + wave*1024); \
  gA0 += 32; gA1 += 32; }while(0)
#define SB_P(bb) do{ \
  g2l16(gB0, (char*)smem + (bb)*BSTR + 8192 + wave*1024); \
  g2l16(gB1, (char*)smem + (bb)*BSTR + 12288 + wave*1024); \
  g2l16(gB2, (char*)smem + (bb)*BSTR + 16384 + wave*1024); \
  g2l16(gB3, (char*)smem + (bb)*BSTR + 20480 + wave*1024); \
  gB0 += 32; gB1 += 32; gB2 += 32; gB3 += 32; }while(0)
#define MM16A do{ \
  __builtin_amdgcn_s_setprio(1); \
  acc[0][0] = MFMA16(af0, bf0, acc[0][0], 0, 0, 0); \
  acc[1][0] = MFMA16(af1, bf0, acc[1][0], 0, 0, 0); \
  acc[0][1] = MFMA16(af0, bf1, acc[0][1], 0, 0, 0); \
  acc[1][1] = MFMA16(af1, bf1, acc[1][1], 0, 0, 0); \
  acc[0][2] = MFMA16(af0, bf2, acc[0][2], 0, 0, 0); \
  acc[1][2] = MFMA16(af1, bf2, acc[1][2], 0, 0, 0); \
  acc[0][3] = MFMA16(af0, bf3, acc[0][3], 0, 0, 0); \
  acc[1][3] = MFMA16(af1, bf3, acc[1][3], 0, 0, 0); \
  acc[0][4] = MFMA16(af0, bf4, acc[0][4], 0, 0, 0); \
  acc[1][4] = MFMA16(af1, bf4, acc[1][4], 0, 0, 0); \
  acc[0][5] = MFMA16(af0, bf5, acc[0][5], 0, 0, 0); \
  acc[1][5] = MFMA16(af1, bf5, acc[1][5], 0, 0, 0); \
  acc[0][6] = MFMA16(af0, bf6, acc[0][6], 0, 0, 0); \
  acc[1][6] = MFMA16(af1, bf6, acc[1][6], 0, 0, 0); \
  acc[0][7] = MFMA16(af0, bf7, acc[0][7], 0, 0, 0); \
  acc[1][7] = MFMA16(af1, bf7, acc[1][7], 0, 0, 0); \
  __builtin_amdgcn_s_setprio(0); }while(0)
#define MM16B do{ \
  __builtin_amdgcn_s_setprio(1); \
  acc[2][0] = MFMA16(af2, bf0, acc[2][0], 0, 0, 0); \
  acc[3][0] = MFMA16(af3, bf0, acc[3][0], 0, 0, 0); \
  acc[2][1] = MFMA16(af2, bf1, acc[2][1], 0, 0, 0); \
  acc[3][1] = MFMA16(af3, bf1, acc[3][1], 0, 0, 0); \
  acc[2][2] = MFMA16(af2, bf2, acc[2][2], 0, 0, 0); \
  acc[3][2] = MFMA16(af3, bf2, acc[3][2], 0, 0, 0); \
  acc[2][3] = MFMA16(af2, bf3, acc[2][3], 0, 0, 0); \
  acc[3][3] = MFMA16(af3, bf3, acc[3][3], 0, 0, 0); \
  acc[2][4] = MFMA16(af2, bf4, acc[2][4], 0, 0, 0); \
  acc[3][4] = MFMA16(af3, bf4, acc[3][4], 0, 0, 0); \
  acc[2][5] = MFMA16(af2, bf5, acc[2][5], 0, 0, 0); \
  acc[3][5] = MFMA16(af3, bf5, acc[3][5], 0, 0, 0); \
  acc[2][6] = MFMA16(af2, bf6, acc[2][6], 0, 0, 0); \
  acc[3][6] = MFMA16(af3, bf6, acc[3][6], 0, 0, 0); \
  acc[2][7] = MFMA16(af2, bf7, acc[2][7], 0, 0, 0); \
  acc[3][7] = MFMA16(af3, bf7, acc[3][7], 0, 0, 0); \
  __builtin_amdgcn_s_setprio(0); }while(0)
#define TILEP(bb, SA, SB, VMX) do{ \
  DS0_P(bb); SA; \
  __builtin_amdgcn_s_barrier(); \
  asm volatile("s_waitcnt lgkmcnt(0)" ::: "memory"); \
  MM16A; \
  __builtin_amdgcn_s_barrier(); \
  DS1_P(bb); SB; \
  __builtin_amdgcn_s_barrier(); \
  asm volatile("s_waitcnt lgkmcnt(0)" ::: "memory"); \
  MM16B; \
  VMX; \
  __builtin_amdgcn_s_barrier(); }while(0)

// common per-thread geometry (4 waves, 256 threads)
#define GEOM_SETUP \
  int tid = threadIdx.x, lane = tid & 63, wave = tid >> 6; \
  int wm = wave >> 1, wn = wave & 1; \
  int l15 = lane & 15, l4 = lane >> 4; \
  int offA0, offA1, offA2, offA3; \
  int offB0, offB1, offB2, offB3, offB4, offB5, offB6, offB7; \
  { int r; \
    r = wm*64 + 0*16 + l15; offA0 = r*64 + ((l4 ^ ((r>>1)&3)) << 4); \
    r = wm*64 + 1*16 + l15; offA1 = r*64 + ((l4 ^ ((r>>1)&3)) << 4); \
    r = wm*64 + 2*16 + l15; offA2 = r*64 + ((l4 ^ ((r>>1)&3)) << 4); \
    r = wm*64 + 3*16 + l15; offA3 = r*64 + ((l4 ^ ((r>>1)&3)) << 4); \
    r = wn*128 + 0*16 + l15; offB0 = 8192 + r*64 + ((l4 ^ ((r>>1)&3)) << 4); \
    r = wn*128 + 1*16 + l15; offB1 = 8192 + r*64 + ((l4 ^ ((r>>1)&3)) << 4); \
    r = wn*128 + 2*16 + l15; offB2 = 8192 + r*64 + ((l4 ^ ((r>>1)&3)) << 4); \
    r = wn*128 + 3*16 + l15; offB3 = 8192 + r*64 + ((l4 ^ ((r>>1)&3)) << 4); \
    r = wn*128 + 4*16 + l15; offB4 = 8192 + r*64 + ((l4 ^ ((r>>1)&3)) << 4); \
    r = wn*128 + 5*16 + l15; offB5 = 8192 + r*64 + ((l4 ^ ((r>>1)&3)) << 4); \
    r = wn*128 + 6*16 + l15; offB6 = 8192 + r*64 + ((l4 ^ ((r>>1)&3)) << 4); \
    r = wn*128 + 7*16 + l15; offB7 = 8192 + r*64 + ((l4 ^ ((r>>1)&3)) << 4); \
  } \
  int rp = tid >> 2, cp = (tid & 3) ^ ((rp >> 1) & 3);  /* stage: row rp(+64k), slot tid&3 */

#define ACC_INIT \
  f32x4 acc[4][8]; \
  _Pragma("unroll") for (int m = 0; m < 4; m++) \
  _Pragma("unroll") for (int n = 0; n < 8; n++) \
  _Pragma("unroll") for (int i = 0; i < 4; i++) acc[m][n][i] = 0.f; \
  s16x8 af0, af1, af2, af3, bf0, bf1, bf2, bf3, bf4, bf5, bf6, bf7;

// ---------- GEMM1: h[slot][DFF] = relu(x[tok] @ W1[e] + b1[e]); K=512, NT=16 ----------
__global__ __launch_bounds__(256, 2) void k_gemm1(
    const uint16_t* __restrict__ xb, const uint16_t* __restrict__ w1t,
    const float* __restrict__ b1,
    const int* __restrict__ tok_of, const int* __restrict__ offsets,
    const int* __restrict__ trB, const int* __restrict__ texp, const int* __restrict__ ntB,
    uint16_t* __restrict__ h) {
  __shared__ __align__(16) uint16_t smem[36864];   // 72KB: 3 bufs x (A 8KB + B 16KB)
  int id = blockIdx.x;
  int nt = *ntB, tpx = (nt + 7) >> 3;
  int x = id & 7, q = id >> 3, j = q >> 3;
  if (j >= tpx) return;
  int tile = x * tpx + j;
  if (tile >= nt) return;
  int n0 = (q & 7) * 256;
  int e = texp[tile], row0 = trB[tile], end = offsets[e + 1];
  GEOM_SETUP;

  const uint16_t *gA0, *gA1, *gB0, *gB1, *gB2, *gB3;
  { int s0 = row0 + rp;      if (s0 >= end) s0 = end - 1;
    int s1 = row0 + rp + 64; if (s1 >= end) s1 = end - 1;
    gA0 = xb + (size_t)(tok_of[s0] >> 1) * DM + cp * 8;
    gA1 = xb + (size_t)(tok_of[s1] >> 1) * DM + cp * 8; }
  { const uint16_t* wb = w1t + (size_t)e * DFF * DM;
    gB0 = wb + (size_t)(n0 + rp +   0) * DM + cp * 8;
    gB1 = wb + (size_t)(n0 + rp +  64) * DM + cp * 8;
    gB2 = wb + (size_t)(n0 + rp + 128) * DM + cp * 8;
    gB3 = wb + (size_t)(n0 + rp + 192) * DM + cp * 8; }

  ACC_INIT;

  SA_P(0); SB_P(0); SA_P(1); SB_P(1);
  VM6;
  __builtin_amdgcn_s_barrier();

#pragma unroll 1
  for (int g = 0; g < 4; ++g) {                    // tiles 0..11 (NT=16)
    TILEP(0, SA_P(2), SB_P(2), VM6);
    TILEP(1, SA_P(0), SB_P(0), VM6);
    TILEP(2, SA_P(1), SB_P(1), VM6);
  }
  TILEP(0, SA_P(2), SB_P(2), VM6);                 // tile 12 stages 14
  TILEP(1, SA_P(0), SB_P(0), VM6);                 // tile 13 stages 15
  TILEP(2, NOSTG, NOSTG, VM0);                     // tile 14
  TILEP(0, NOSTG, NOSTG, NOVM);                    // tile 15

  // epilogue: bias+relu -> bf16, per-wave LDS repack (row stride 272B: 16B-aligned, bank-spread)
  {
    float bv[8];
#pragma unroll
    for (int n = 0; n < 8; n++) bv[n] = b1[(size_t)e * DFF + n0 + wn * 128 + n * 16 + l15];
    char* wrg = (char*)smem + wave * 4608;
    int rr = lane >> 2, cb = lane & 3;
#pragma unroll
    for (int m = 0; m < 4; m++) {
#pragma unroll
      for (int n = 0; n < 8; n++)
#pragma unroll
        for (int i = 0; i < 4; i++) {
          float v = fmaxf(acc[m][n][i] + bv[n], 0.f);
          *(uint16_t*)(wrg + (l4 * 4 + i) * 272 + (n * 16 + l15) * 2) = f2b(v);
        }
      int gr = row0 + wm * 64 + m * 16 + rr;
      const char* src = wrg + rr * 272 + cb * 64;
      if (gr < end) {
        uint16_t* dst = h + (size_t)gr * DFF + n0 + wn * 128 + cb * 32;
        *(s16x8*)(dst +  0) = *(const s16x8*)(src +  0);
        *(s16x8*)(dst +  8) = *(const s16x8*)(src + 16);
        *(s16x8*)(dst + 16) = *(const s16x8*)(src + 32);
        *(s16x8*)(dst + 24) = *(const s16x8*)(src + 48);
      }
    }
  }
}

// ---------- GEMM2: y32[pair] = w_of[slot]*(h[slot] @ W2[e] + b2[e]); K=2048, NT=64 ----------
// Output indexed by PAIR (tok*2+k) so combine is a streaming add of adjacent rows.
__global__ __launch_bounds__(256, 2) void k_gemm2(
    const uint16_t* __restrict__ h, const uint16_t* __restrict__ w2t,
    const float* __restrict__ b2, const float* __restrict__ w_of,
    const int* __restrict__ tok_of, const int* __restrict__ offsets,
    const int* __restrict__ trB, const int* __restrict__ texp, const int* __restrict__ ntB,
    float* __restrict__ y32) {
  __shared__ __align__(16) uint16_t smem[36864];   // 72KB: 3 bufs x (A 8KB + B 16KB)
  int id = blockIdx.x;
  int nt = *ntB, tpx = (nt + 7) >> 3;
  int x = id & 7, q = id >> 3, j = q >> 1;
  if (j >= tpx) return;
  int tile = x * tpx + j;
  if (tile >= nt) return;
  int n0 = (q & 1) * 256;
  int e = texp[tile], row0 = trB[tile], end = offsets[e + 1];
  GEOM_SETUP;

  const uint16_t *gA0, *gA1, *gB0, *gB1, *gB2, *gB3;
  { int s0 = row0 + rp;      if (s0 >= end) s0 = end - 1;
    int s1 = row0 + rp + 64; if (s1 >= end) s1 = end - 1;
    gA0 = h + (size_t)s0 * DFF + cp * 8;
    gA1 = h + (size_t)s1 * DFF + cp * 8; }
  { const uint16_t* wb = w2t + (size_t)e * DM * DFF;
    gB0 = wb + (size_t)(n0 + rp +   0) * DFF + cp * 8;
    gB1 = wb + (size_t)(n0 + rp +  64) * DFF + cp * 8;
    gB2 = wb + (size_t)(n0 + rp + 128) * DFF + cp * 8;
    gB3 = wb + (size_t)(n0 + rp + 192) * DFF + cp * 8; }

  ACC_INIT;

  SA_P(0); SB_P(0); SA_P(1); SB_P(1);
  VM6;
  __builtin_amdgcn_s_barrier();

#pragma unroll 1
  for (int g = 0; g < 20; ++g) {                   // tiles 0..59 (NT=64)
    TILEP(0, SA_P(2), SB_P(2), VM6);
    TILEP(1, SA_P(0), SB_P(0), VM6);
    TILEP(2, SA_P(1), SB_P(1), VM6);
  }
  TILEP(0, SA_P(2), SB_P(2), VM6);                 // tile 60 stages 62
  TILEP(1, SA_P(0), SB_P(0), VM6);                 // tile 61 stages 63
  TILEP(2, NOSTG, NOSTG, VM0);                     // tile 62
  TILEP(0, NOSTG, NOSTG, NOVM);                    // tile 63

  // epilogue: weighted bias add, fp32 stores into pair-indexed y32 (16-lane 64B runs)
  {
    float bv[8];
#pragma unroll
    for (int n = 0; n < 8; n++) bv[n] = b2[(size_t)e * DM + n0 + wn * 128 + n * 16 + l15];
#pragma unroll
    for (int m = 0; m < 4; m++)
#pragma unroll
      for (int i = 0; i < 4; i++) {
        int slot = row0 + wm * 64 + m * 16 + l4 * 4 + i;
        if (slot < end) {
          float wgt = w_of[slot];
          int pr = tok_of[slot];                   // pair index = tok*2 + k
          size_t base = (size_t)pr * DM + n0 + wn * 128 + l15;
#pragma unroll
          for (int n = 0; n < 8; n++) y32[base + n * 16] = wgt * (acc[m][n][i] + bv[n]);
        }
      }
  }
}

// ---------------- combine: out[tok] = y32[2tok] + y32[2tok+1] (streaming, no indirection) ----------------
__global__ __launch_bounds__(256) void k_combine(const float* __restrict__ y32,
                                                 float* __restrict__ out) {
  int tid = threadIdx.x;
  int tok = blockIdx.x * 2 + (tid >> 7);
  int c4 = (tid & 127) * 4;
  const float4 a = *(const float4*)(y32 + (size_t)(tok * 2)     * DM + c4);
  const float4 b = *(const float4*)(y32 + (size_t)(tok * 2 + 1) * DM + c4);
  *(float4*)(out + (size_t)tok * DM + c4) = make_float4(a.x + b.x, a.y + b.y, a.z + b.z, a.w + b.w);
}

extern "C" void kernel_launch(void* const* d_in, const int* in_sizes, int n_in,
                              void* d_out, int out_size, void* d_ws, size_t ws_size,
                              hipStream_t stream) {
  const float* x  = (const float*)d_in[0];
  const float* wg = (const float*)d_in[1];
  const float* w1 = (const float*)d_in[2];
  const float* b1 = (const float*)d_in[3];
  const float* w2 = (const float*)d_in[4];
  const float* b2 = (const float*)d_in[5];
  float* out = (float*)d_out;

  char* ws = (char*)d_ws;
  const size_t MB = 1024 * 1024;
  uint16_t* xb   = (uint16_t*)ws;                  // [0,16) MB
  uint16_t* w1t  = (uint16_t*)(ws + 16 * MB);      // [16,32) MB  [E][DFF][DM]
  uint16_t* w2t  = (uint16_t*)(ws + 32 * MB);      // [32,48) MB  [E][DM][DFF]
  uint16_t* hbuf = (uint16_t*)(ws + 48 * MB);      // [48,176) MB [NPAIR][DFF]
  int* ctrl = (int*)(ws + 176 * MB);               // [176,177) MB
  int*   counts  = ctrl;                 // 0..8
  int*   cursors = ctrl + 8;             // 8..16
  int*   offsets = ctrl + 16;            // 16..25
  int*   ntB     = ctrl + 32;            // 32
  int*   trB     = ctrl + 64;            // 64..384 (320)
  int*   texp    = ctrl + 384;           // 384..704 (320)
  int*   tk_e    = ctrl + 1024;
  float* tk_w    = (float*)(ctrl + 1024 + 32768);
  int*   tok_of  = ctrl + 1024 + 2 * 32768;
  float* w_of    = (float*)(ctrl + 1024 + 3 * 32768);
  float* y32     = (float*)(ws + 177 * MB);        // [177,241) MB fp32 [NPAIR][DM]

  hipMemsetAsync(counts, 0, 16 * sizeof(int), stream);

  k_prep<<<256 + 16384, 256, 0, stream>>>(x, wg, counts, tk_e, tk_w, xb,
                                          w1, w2, w1t, w2t);
  k_build<<<NPAIR / 256, 256, 0, stream>>>(tk_e, tk_w, counts, cursors, tok_of, w_of,
                                           offsets, trB, texp, ntB);
  k_gemm1<<<8 * TPXMAX * 8, 256, 0, stream>>>(xb, w1t, b1, tok_of, offsets,
                                              trB, texp, ntB, hbuf);
  k_gemm2<<<8 * TPXMAX * 2, 256, 0, stream>>>(hbuf, w2t, b2, w_of, tok_of, offsets,
                                              trB, texp, ntB, y32);
  k_combine<<<BTOK / 2, 256, 0, stream>>>(y32, out);
}